// Round 15
// baseline (179.793 us; speedup 1.0000x reference)
//
#include <hip/hip_runtime.h>
#include <hip/hip_bf16.h>

#define NN 50000
#define NE 800000
#define SCAN_NB ((NN + 255) / 256)   // 196 blocks
#define G1_NB ((NN + 63) / 64)       // 782 blocks == (NE+1023)/1024
#define A1_NB ((NN + 3) / 4)         // 12500 blocks
#define NXCC 8
// IN=128, HID=32, HEADS=4, HC=128, OUT=40, EDIM=5

typedef float f32x4_t __attribute__((ext_vector_type(4)));
typedef float f32x2_t __attribute__((ext_vector_type(2)));
typedef short s16x8_t __attribute__((ext_vector_type(8)));

// bf16 pack/unpack helpers (RNE rounding).
__device__ __forceinline__ unsigned f2bf2(float a, float b) {
    unsigned ua = __float_as_uint(a);
    ua = (ua + 0x7fffu + ((ua >> 16) & 1u)) >> 16;
    unsigned ub = __float_as_uint(b);
    ub = (ub + 0x7fffu + ((ub >> 16) & 1u)) >> 16;
    return ua | (ub << 16);
}
__device__ __forceinline__ float bf_lo(unsigned u) { return __uint_as_float(u << 16); }
__device__ __forceinline__ float bf_hi(unsigned u) { return __uint_as_float(u & 0xffff0000u); }
__device__ __forceinline__ f32x2_t bfpair(unsigned u) {
    return (f32x2_t){__uint_as_float(u << 16), __uint_as_float(u & 0xffff0000u)};
}

// ---------------------------------------------------------------------------
// K0: prep — zero the 8 cnt replicas (grid-wide) + folds + bf16 GEMM weights.
__global__ __launch_bounds__(256) void prep_kernel(
    const float* __restrict__ We1, const float* __restrict__ ae1w,
    const float* __restrict__ We2, const float* __restrict__ ae2w,
    const float* __restrict__ W1, const float* __restrict__ W2,
    float* __restrict__ wf1, float* __restrict__ wf2,
    unsigned* __restrict__ w1t, unsigned* __restrict__ w2t,
    int* __restrict__ cnt_rep) {
    int t = threadIdx.x;
    int g = blockIdx.x * 256 + t;
    if (g < NN) {
#pragma unroll
        for (int k = 0; k < NXCC; ++k) cnt_rep[(size_t)k * NN + g] = 0;
    }
    if (blockIdx.x != 0) return;
    if (t < 20) {
        int j = t >> 2, h = t & 3;
        float s = 0.f;
        for (int c = 0; c < 32; ++c) s += We1[j * 128 + h * 32 + c] * ae1w[h * 32 + c];
        wf1[j * 4 + h] = s;
    }
    if (t >= 32 && t < 37) {
        int j = t - 32;
        float s = 0.f;
        for (int c = 0; c < 40; ++c) s += We2[j * 40 + c] * ae2w[c];
        wf2[j] = s;
    }
    for (int i = t; i < 128 * 64; i += 256) {
        int c = i >> 6, kp = i & 63;
        w1t[i] = f2bf2(W1[(size_t)(2 * kp) * 128 + c], W1[(size_t)(2 * kp + 1) * 128 + c]);
    }
    for (int i = t; i < 48 * 64; i += 256) {
        int c = i >> 6, kp = i & 63;
        w2t[i] = (c < 40) ? f2bf2(W2[(size_t)(2 * kp) * 40 + c], W2[(size_t)(2 * kp + 1) * 40 + c]) : 0u;
    }
}

// ---------------------------------------------------------------------------
// K1: count via XCD-LOCAL workgroup-scope atomics. Each wave increments its
// own XCD's replica (runtime XCC_ID), so the RMW executes in the local L2
// (~150cy) instead of the cross-XCD fabric (~600-900cy). Each replica slice
// is touched by exactly one XCD -> single-L2 serialization is coherent;
// kernel-boundary flush publishes. rank packs (xcc<<24 | local_rank).
__global__ __launch_bounds__(256) void count_kernel(const int* __restrict__ dst0,
                                                    int* __restrict__ cnt_rep,
                                                    int* __restrict__ rank) {
    unsigned xcc;
    asm volatile("s_getreg_b32 %0, hwreg(HW_REG_XCC_ID)" : "=s"(xcc));
    xcc &= (NXCC - 1);
    int* myc = cnt_rep + (size_t)xcc * NN;
    int base = blockIdx.x * 1024 + threadIdx.x;
#pragma unroll
    for (int k = 0; k < 4; ++k) {
        int e = base + k * 256;
        if (e < NE) {
            int r = __hip_atomic_fetch_add(&myc[dst0[e]], 1, __ATOMIC_RELAXED,
                                           __HIP_MEMORY_SCOPE_WORKGROUP);
            rank[e] = (int)((xcc << 24) | (unsigned)r);
        }
    }
}

// ---------------------------------------------------------------------------
// K2: MFMA GEMM1: xs1[N,128](bf16) = x[N,128] @ W1[128,128].
__global__ __launch_bounds__(256) void gemm1_mfma(
    const float* __restrict__ A, const unsigned* __restrict__ w1t,
    unsigned* __restrict__ out) {
    __shared__ unsigned sA[64 * 68];
    __shared__ unsigned sB[128 * 68];
    int t = threadIdx.x;
    int row0 = blockIdx.x * 64;
    for (int i = t; i < 64 * 32; i += 256) {
        int r = i >> 5, q = i & 31;
        int gr = row0 + r;
        float4 v = (gr < NN) ? *(const float4*)&A[(size_t)gr * 128 + q * 4]
                             : make_float4(0.f, 0.f, 0.f, 0.f);
        sA[r * 68 + q * 2]     = f2bf2(v.x, v.y);
        sA[r * 68 + q * 2 + 1] = f2bf2(v.z, v.w);
    }
    for (int i = t; i < 128 * 16; i += 256) {
        int c = i >> 4, q = i & 15;
        *(uint4*)&sB[c * 68 + q * 4] = *(const uint4*)&w1t[c * 64 + q * 4];
    }
    __syncthreads();
    int wv = t >> 6, lane = t & 63;
    int lr = lane & 15, kgrp = lane >> 4;
    f32x4_t acc[8];
#pragma unroll
    for (int i = 0; i < 8; ++i) acc[i] = (f32x4_t){0.f, 0.f, 0.f, 0.f};
    int arow = wv * 16 + lr;
#pragma unroll
    for (int kt = 0; kt < 4; ++kt) {
        int kw = kt * 16 + kgrp * 4;
        s16x8_t af = *(const s16x8_t*)&sA[arow * 68 + kw];
#pragma unroll
        for (int tc = 0; tc < 8; ++tc) {
            s16x8_t bf = *(const s16x8_t*)&sB[(tc * 16 + lr) * 68 + kw];
            acc[tc] = __builtin_amdgcn_mfma_f32_16x16x32_bf16(af, bf, acc[tc], 0, 0, 0);
        }
    }
    int orow0 = row0 + wv * 16 + kgrp * 4;
#pragma unroll
    for (int tc = 0; tc < 8; ++tc) {
#pragma unroll
        for (int r = 0; r < 4; ++r) {
            float v = acc[tc][r];
            float other = __shfl_xor(v, 1);
            int gr = orow0 + r;
            if (!(lane & 1) && gr < NN)
                out[(size_t)gr * 64 + tc * 8 + (lr >> 1)] = f2bf2(v, other);
        }
    }
}

// ---------------------------------------------------------------------------
// K3: MERGED [scan1+replica-combine || alpha1].
__global__ __launch_bounds__(256) void scan1_alpha1(
    const int* __restrict__ cnt_rep, int* __restrict__ off, int* __restrict__ bsum,
    int* __restrict__ rpre, int* __restrict__ ctot,
    const unsigned* __restrict__ xs1u, const float* __restrict__ asw,
    const float* __restrict__ adw, float* __restrict__ as1, float* __restrict__ ad1) {
    if (blockIdx.x < SCAN_NB) {
        __shared__ int tmp[256];
        int t = threadIdx.x;
        int g = blockIdx.x * 256 + t;
        int v = 0;
        if (g < NN) {
            int pre[NXCC];
            int tot = 0;
#pragma unroll
            for (int k = 0; k < NXCC; ++k) {
                pre[k] = tot;
                tot += cnt_rep[(size_t)k * NN + g];
            }
            *(int4*)&rpre[(size_t)g * 8]     = make_int4(pre[0], pre[1], pre[2], pre[3]);
            *(int4*)&rpre[(size_t)g * 8 + 4] = make_int4(pre[4], pre[5], pre[6], pre[7]);
            ctot[g] = tot;
            v = tot;
        }
        tmp[t] = v;
        __syncthreads();
#pragma unroll
        for (int d = 1; d < 256; d <<= 1) {
            int u = (t >= d) ? tmp[t - d] : 0;
            __syncthreads();
            tmp[t] += u;
            __syncthreads();
        }
        if (g < NN) off[g] = tmp[t] - v;
        if (t == 255) bsum[blockIdx.x] = tmp[255];
        return;
    }
    int wid = ((blockIdx.x - SCAN_NB) * 256 + threadIdx.x) >> 6;
    if (wid >= NN) return;
    int lane = threadIdx.x & 63;
    int c = lane * 2;
    unsigned u = xs1u[(size_t)wid * 64 + lane];
    float vx = bf_lo(u), vy = bf_hi(u);
    float pa = vx * asw[c] + vy * asw[c + 1];
    float pd = vx * adw[c] + vy * adw[c + 1];
#pragma unroll
    for (int d = 8; d >= 1; d >>= 1) {
        pa += __shfl_xor(pa, d, 16);
        pd += __shfl_xor(pd, d, 16);
    }
    if ((lane & 15) == 0) {
        as1[wid * 4 + (lane >> 4)] = pa;
        ad1[wid * 4 + (lane >> 4)] = pd;
    }
}

// ---------------------------------------------------------------------------
// K4: scan finalize — each block redundantly scans the 196 raw block sums.
__global__ __launch_bounds__(256) void scan3_kernel(int* __restrict__ off,
                                                    const int* __restrict__ bsum,
                                                    const int* __restrict__ ctot) {
    __shared__ int tmp[256];
    int t = threadIdx.x;
    int v = (t < SCAN_NB) ? bsum[t] : 0;
    tmp[t] = v;
    __syncthreads();
#pragma unroll
    for (int d = 1; d < 256; d <<= 1) {
        int u = (t >= d) ? tmp[t - d] : 0;
        __syncthreads();
        tmp[t] += u;
        __syncthreads();
    }
    int pre = (blockIdx.x == 0) ? 0 : tmp[blockIdx.x - 1];
    int g = blockIdx.x * 256 + t;
    if (g < NN) {
        int o = off[g] + pre;
        off[g] = o;
        if (g == NN - 1) off[NN] = o + ctot[g];
    }
}

// ---------------------------------------------------------------------------
// K5: fill CSR, atomic-free: pos = off[dst] + rpre[dst*8+xcc] + local_rank.
__global__ __launch_bounds__(256) void fill_fold_kernel(
    const int* __restrict__ src0, const int* __restrict__ dst0,
    const float* __restrict__ eattr, const float* __restrict__ wf1,
    const float* __restrict__ wf2, const int* __restrict__ off,
    const int* __restrict__ rank, const int* __restrict__ rpre,
    uint4* __restrict__ epk) {
    int base = blockIdx.x * 1024 + threadIdx.x;
#pragma unroll
    for (int k = 0; k < 4; ++k) {
        int e = base + k * 256;
        if (e >= NE) continue;
        float a[5];
#pragma unroll
        for (int j = 0; j < 5; ++j) a[j] = eattr[(size_t)e * 5 + j];
        float o[4];
#pragma unroll
        for (int h = 0; h < 4; ++h) {
            float s = 0.f;
#pragma unroll
            for (int j = 0; j < 5; ++j) s += a[j] * wf1[j * 4 + h];
            o[h] = s;
        }
        float s2 = 0.f;
#pragma unroll
        for (int j = 0; j < 5; ++j) s2 += a[j] * wf2[j];
        int d = dst0[e];
        unsigned rk = (unsigned)rank[e];
        int pos = off[d] + rpre[(size_t)d * 8 + (rk >> 24)] + (int)(rk & 0xFFFFFFu);
        epk[pos] = make_uint4((unsigned)src0[e], f2bf2(o[0], o[1]), f2bf2(o[2], o[3]),
                              __float_as_uint(s2));
    }
}

// ---------------------------------------------------------------------------
// K6: layer-1 GAT aggregation. 4 nodes/wave, 16 lanes/node; 8 edges in
// flight per iteration (16-entry LDS chunk zero-padded).
__global__ __launch_bounds__(256) void gat1_kernel(
    const uint4* __restrict__ epk, const int* __restrict__ off,
    const unsigned* __restrict__ xs1u,
    const float4* __restrict__ as1, const float4* __restrict__ ad1,
    const float* __restrict__ b1, const float* __restrict__ g1, const float* __restrict__ be1,
    const float* __restrict__ rm1, const float* __restrict__ rv1, unsigned* __restrict__ h1u) {
    __shared__ int   lds_s[4][4][16];
    __shared__ float lds_w[4][4][16][4];
    int wave = threadIdx.x >> 6;
    int lane = threadIdx.x & 63;
    int g = lane >> 4;
    int lr = lane & 15;
    int qh = lr >> 2;
    int n = blockIdx.x * 16 + wave * 4 + g;
    int e0 = off[n];
    int deg = off[n + 1] - e0;
    float4 adn = ad1[n];
    float4 asn = as1[n];
    f32x2_t acc2[4];
#pragma unroll
    for (int k = 0; k < 4; ++k) acc2[k] = (f32x2_t){0.f, 0.f};
    float ds0 = 0.f, ds1 = 0.f, ds2 = 0.f, ds3 = 0.f;
    float s0 = 0.f, s1 = 0.f, s2 = 0.f, s3 = 0.f;
    int mc = (deg + 15) >> 4;
    mc = max(mc, __shfl_xor(mc, 16));
    mc = max(mc, __shfl_xor(mc, 32));

    for (int ch = 0; ch < mc; ++ch) {
        int i = ch * 16 + lr;
        int s = 0;
        float w0 = 0.f, w1 = 0.f, w2 = 0.f, w3 = 0.f;
        if (i < deg) {
            uint4 ep = epk[e0 + i];
            s = (int)ep.x;
            float ax = bf_lo(ep.y), ay = bf_hi(ep.y);
            float az = bf_lo(ep.z), aw = bf_hi(ep.z);
            float4 av = as1[s];
            float a0 = av.x + adn.x + ax;
            float a1 = av.y + adn.y + ay;
            float a2 = av.z + adn.z + az;
            float a3 = av.w + adn.w + aw;
            a0 = a0 >= 0.f ? a0 : 0.2f * a0;
            a1 = a1 >= 0.f ? a1 : 0.2f * a1;
            a2 = a2 >= 0.f ? a2 : 0.2f * a2;
            a3 = a3 >= 0.f ? a3 : 0.2f * a3;
            w0 = __expf(a0); w1 = __expf(a1); w2 = __expf(a2); w3 = __expf(a3);
            ds0 += w0; ds1 += w1; ds2 += w2; ds3 += w3;
            s0 += ax; s1 += ay; s2 += az; s3 += aw;
        }
        lds_s[wave][g][lr] = s;
        *(float4*)&lds_w[wave][g][lr][0] = make_float4(w0, w1, w2, w3);
        __builtin_amdgcn_wave_barrier();
        int cn = deg - ch * 16;
        cn = cn > 16 ? 16 : (cn < 0 ? 0 : cn);
        int cnr = (cn + 7) & ~7;
        for (int j = 0; j < cnr; j += 8) {
            int sj[8];
            float ww[8];
            uint4 uu[8];
#pragma unroll
            for (int q2 = 0; q2 < 8; ++q2) {
                sj[q2] = lds_s[wave][g][j + q2];
                ww[q2] = lds_w[wave][g][j + q2][qh];
            }
#pragma unroll
            for (int q2 = 0; q2 < 8; ++q2)
                uu[q2] = *(const uint4*)&xs1u[(size_t)sj[q2] * 64 + lr * 4];
#pragma unroll
            for (int q2 = 0; q2 < 8; ++q2) {
                f32x2_t W = {ww[q2], ww[q2]};
                acc2[0] += W * bfpair(uu[q2].x);
                acc2[1] += W * bfpair(uu[q2].y);
                acc2[2] += W * bfpair(uu[q2].z);
                acc2[3] += W * bfpair(uu[q2].w);
            }
        }
        __builtin_amdgcn_wave_barrier();
    }
#pragma unroll
    for (int d = 8; d >= 1; d >>= 1) {
        ds0 += __shfl_xor(ds0, d, 16); ds1 += __shfl_xor(ds1, d, 16);
        ds2 += __shfl_xor(ds2, d, 16); ds3 += __shfl_xor(ds3, d, 16);
        s0 += __shfl_xor(s0, d, 16);   s1 += __shfl_xor(s1, d, 16);
        s2 += __shfl_xor(s2, d, 16);   s3 += __shfl_xor(s3, d, 16);
    }
    float invd = 1.f / fmaxf((float)deg, 1.f);
    float aL0 = asn.x + adn.x + s0 * invd;
    float aL1 = asn.y + adn.y + s1 * invd;
    float aL2 = asn.z + adn.z + s2 * invd;
    float aL3 = asn.w + adn.w + s3 * invd;
    aL0 = aL0 >= 0.f ? aL0 : 0.2f * aL0;
    aL1 = aL1 >= 0.f ? aL1 : 0.2f * aL1;
    aL2 = aL2 >= 0.f ? aL2 : 0.2f * aL2;
    aL3 = aL3 >= 0.f ? aL3 : 0.2f * aL3;
    float ws0 = __expf(aL0), ws1 = __expf(aL1), ws2 = __expf(aL2), ws3 = __expf(aL3);
    float wself = qh == 0 ? ws0 : (qh == 1 ? ws1 : (qh == 2 ? ws2 : ws3));
    float dh = qh == 0 ? ds0 + ws0 : (qh == 1 ? ds1 + ws1 : (qh == 2 ? ds2 + ws2 : ds3 + ws3));
    uint4 us = *(const uint4*)&xs1u[(size_t)n * 64 + lr * 4];
    f32x2_t Ws = {wself, wself};
    acc2[0] += Ws * bfpair(us.x); acc2[1] += Ws * bfpair(us.y);
    acc2[2] += Ws * bfpair(us.z); acc2[3] += Ws * bfpair(us.w);
    float inv = 1.f / (dh + 1e-16f);
    int c = lr * 8;
    uint4 ou;
    unsigned* op = (unsigned*)&ou;
#pragma unroll
    for (int k2 = 0; k2 < 4; ++k2) {
        int c0 = c + 2 * k2, c1 = c + 2 * k2 + 1;
        float o0 = acc2[k2][0] * inv + b1[c0];
        float o1 = acc2[k2][1] * inv + b1[c1];
        float sc0 = g1[c0] * rsqrtf(rv1[c0] + 1e-5f);
        float sc1 = g1[c1] * rsqrtf(rv1[c1] + 1e-5f);
        o0 = (o0 - rm1[c0]) * sc0 + be1[c0];
        o1 = (o1 - rm1[c1]) * sc1 + be1[c1];
        o0 = o0 > 0.f ? o0 : __expf(o0) - 1.f;
        o1 = o1 > 0.f ? o1 : __expf(o1) - 1.f;
        op[k2] = f2bf2(o0, o1);
    }
    *(uint4*)&h1u[(size_t)n * 64 + lr * 4] = ou;
}

// ---------------------------------------------------------------------------
// K7: MFMA GEMM2: xs2[N,40](bf16, stride 64) = h1(bf16) @ W2(bf16,48-pad).
__global__ __launch_bounds__(256) void gemm2_mfma(
    const unsigned* __restrict__ A, const unsigned* __restrict__ w2t,
    unsigned* __restrict__ out) {
    __shared__ unsigned sA[64 * 68];
    __shared__ unsigned sB[48 * 68];
    int t = threadIdx.x;
    int row0 = blockIdx.x * 64;
    for (int i = t; i < 64 * 16; i += 256) {
        int r = i >> 4, q = i & 15;
        int gr = row0 + r;
        uint4 v = (gr < NN) ? *(const uint4*)&A[(size_t)gr * 64 + q * 4]
                            : make_uint4(0u, 0u, 0u, 0u);
        *(uint4*)&sA[r * 68 + q * 4] = v;
    }
    for (int i = t; i < 48 * 16; i += 256) {
        int c = i >> 4, q = i & 15;
        *(uint4*)&sB[c * 68 + q * 4] = *(const uint4*)&w2t[c * 64 + q * 4];
    }
    __syncthreads();
    int wv = t >> 6, lane = t & 63;
    int lr = lane & 15, kgrp = lane >> 4;
    f32x4_t acc[3];
#pragma unroll
    for (int i = 0; i < 3; ++i) acc[i] = (f32x4_t){0.f, 0.f, 0.f, 0.f};
    int arow = wv * 16 + lr;
#pragma unroll
    for (int kt = 0; kt < 4; ++kt) {
        int kw = kt * 16 + kgrp * 4;
        s16x8_t af = *(const s16x8_t*)&sA[arow * 68 + kw];
#pragma unroll
        for (int tc = 0; tc < 3; ++tc) {
            s16x8_t bf = *(const s16x8_t*)&sB[(tc * 16 + lr) * 68 + kw];
            acc[tc] = __builtin_amdgcn_mfma_f32_16x16x32_bf16(af, bf, acc[tc], 0, 0, 0);
        }
    }
    int orow0 = row0 + wv * 16 + kgrp * 4;
#pragma unroll
    for (int tc = 0; tc < 3; ++tc) {
#pragma unroll
        for (int r = 0; r < 4; ++r) {
            float v = acc[tc][r];
            float other = __shfl_xor(v, 1);
            int gr = orow0 + r;
            if (!(lane & 1) && gr < NN && (tc < 2 || lr < 8))
                out[(size_t)gr * 32 + tc * 8 + (lr >> 1)] = f2bf2(v, other);
        }
    }
}

// ---------------------------------------------------------------------------
// K8: per-node attention coefficients layer 2 (from bf16 xs2).
__global__ __launch_bounds__(256) void alpha2_kernel(
    const unsigned* __restrict__ xs2u, const float* __restrict__ asw,
    const float* __restrict__ adw, float* __restrict__ as2, float* __restrict__ ad2) {
    int wid = (blockIdx.x * 256 + threadIdx.x) >> 6;
    if (wid >= NN) return;
    int lane = threadIdx.x & 63;
    float pa = 0.f, pd = 0.f;
    if (lane < 20) {
        unsigned u = xs2u[(size_t)wid * 32 + lane];
        float vx = bf_lo(u), vy = bf_hi(u);
        int c = lane * 2;
        pa = vx * asw[c] + vy * asw[c + 1];
        pd = vx * adw[c] + vy * adw[c + 1];
    }
#pragma unroll
    for (int d = 16; d >= 1; d >>= 1) {
        pa += __shfl_xor(pa, d, 32);
        pd += __shfl_xor(pd, d, 32);
    }
    if (lane == 0) { as2[wid] = pa; ad2[wid] = pd; }
}

// ---------------------------------------------------------------------------
// K9: layer-2 GAT aggregation + bias + BN + log_softmax.
__global__ __launch_bounds__(256) void gat2_kernel(
    const uint4* __restrict__ epk, const int* __restrict__ off,
    const unsigned* __restrict__ xs2u,
    const float* __restrict__ as2, const float* __restrict__ ad2,
    const float* __restrict__ b2, const float* __restrict__ g2, const float* __restrict__ be2,
    const float* __restrict__ rm2, const float* __restrict__ rv2, float* __restrict__ outp) {
    __shared__ int   lds_s[4][72];
    __shared__ float lds_w[4][72];
    int wid = (blockIdx.x * 256 + threadIdx.x) >> 6;
    if (wid >= NN) return;
    int lane = threadIdx.x & 63;
    int warp = threadIdx.x >> 6;
    int n = wid;
    int e0 = off[n], e1 = off[n + 1];
    int deg = e1 - e0;
    int grp3 = lane / 20;
    int col = lane - grp3 * 20;
    bool act = grp3 < 3;
    int grpo = act ? grp3 : 0;
    if (lane < 8) {
        lds_s[warp][64 + lane] = 0;
        lds_w[warp][64 + lane] = 0.f;
    }
    float adn = ad2[n];
    float asn = as2[n];
    f32x2_t acc2 = {0.f, 0.f};
    float dsum = 0.f, aesum = 0.f;

    for (int base = 0; base < deg; base += 64) {
        int i = base + lane;
        int cn = min(64, deg - base);
        int s = 0;
        float w = 0.f;
        if (i < deg) {
            uint4 ep = epk[e0 + i];
            s = (int)ep.x;
            float ae = __uint_as_float(ep.w);
            float a = as2[s] + adn + ae;
            a = a >= 0.f ? a : 0.2f * a;
            w = __expf(a);
            dsum += w;
            aesum += ae;
        }
        lds_s[warp][lane] = s;
        lds_w[warp][lane] = w;
        __builtin_amdgcn_wave_barrier();
        int cnr = ((cn + 11) / 12) * 12;            // <= 72; jj max = 71
        for (int j = 0; j < cnr; j += 12) {
            int jj0 = j + grpo, jj1 = jj0 + 3, jj2 = jj0 + 6, jj3 = jj0 + 9;
            int sj0 = lds_s[warp][jj0];
            int sj1 = lds_s[warp][jj1];
            int sj2 = lds_s[warp][jj2];
            int sj3 = lds_s[warp][jj3];
            float w0 = act ? lds_w[warp][jj0] : 0.f;
            float w1 = act ? lds_w[warp][jj1] : 0.f;
            float w2 = act ? lds_w[warp][jj2] : 0.f;
            float w3 = act ? lds_w[warp][jj3] : 0.f;
            unsigned u0 = xs2u[(size_t)sj0 * 32 + col];
            unsigned u1 = xs2u[(size_t)sj1 * 32 + col];
            unsigned u2 = xs2u[(size_t)sj2 * 32 + col];
            unsigned u3 = xs2u[(size_t)sj3 * 32 + col];
            acc2 += (f32x2_t){w0, w0} * bfpair(u0);
            acc2 += (f32x2_t){w1, w1} * bfpair(u1);
            acc2 += (f32x2_t){w2, w2} * bfpair(u2);
            acc2 += (f32x2_t){w3, w3} * bfpair(u3);
        }
        __builtin_amdgcn_wave_barrier();
    }
    {
        float p0 = __shfl(acc2[0], (lane + 20) & 63);
        float p1 = __shfl(acc2[1], (lane + 20) & 63);
        float q0 = __shfl(acc2[0], (lane + 40) & 63);
        float q1 = __shfl(acc2[1], (lane + 40) & 63);
        acc2[0] += p0 + q0;
        acc2[1] += p1 + q1;
    }
#pragma unroll
    for (int d = 32; d >= 1; d >>= 1) {
        dsum += __shfl_xor(dsum, d);
        aesum += __shfl_xor(aesum, d);
    }
    float invd = 1.f / fmaxf((float)deg, 1.f);
    float aL = asn + adn + aesum * invd;
    aL = aL >= 0.f ? aL : 0.2f * aL;
    float wself = __expf(aL);
    float denom = dsum + wself;

    float v0 = 0.f, v1 = 0.f;
    if (lane < 20) {
        unsigned u = xs2u[(size_t)n * 32 + lane];
        acc2[0] += wself * bf_lo(u);
        acc2[1] += wself * bf_hi(u);
        int c = lane * 2;
        float inv = 1.f / (denom + 1e-16f);
        v0 = acc2[0] * inv + b2[c];
        v1 = acc2[1] * inv + b2[c + 1];
        float sc0 = g2[c] * rsqrtf(rv2[c] + 1e-5f);
        float sc1 = g2[c + 1] * rsqrtf(rv2[c + 1] + 1e-5f);
        v0 = (v0 - rm2[c]) * sc0 + be2[c];
        v1 = (v1 - rm2[c + 1]) * sc1 + be2[c + 1];
    }
    float mx = (lane < 20) ? fmaxf(v0, v1) : -3.0e38f;
#pragma unroll
    for (int d = 32; d >= 1; d >>= 1) mx = fmaxf(mx, __shfl_xor(mx, d));
    float ex = (lane < 20) ? __expf(v0 - mx) + __expf(v1 - mx) : 0.f;
#pragma unroll
    for (int d = 32; d >= 1; d >>= 1) ex += __shfl_xor(ex, d);
    if (lane < 20) {
        float ls = __logf(ex);
        *(float2*)&outp[(size_t)n * 40 + lane * 2] = make_float2(v0 - mx - ls, v1 - mx - ls);
    }
}

// ---------------------------------------------------------------------------
extern "C" void kernel_launch(void* const* d_in, const int* in_sizes, int n_in,
                              void* d_out, int out_size, void* d_ws, size_t ws_size,
                              hipStream_t stream) {
    const float* x     = (const float*)d_in[0];
    const int*   ei    = (const int*)d_in[1];
    const float* eattr = (const float*)d_in[2];
    const float* W1    = (const float*)d_in[3];
    const float* as1w  = (const float*)d_in[4];
    const float* ad1w  = (const float*)d_in[5];
    const float* ae1w  = (const float*)d_in[6];
    const float* We1   = (const float*)d_in[7];
    const float* b1    = (const float*)d_in[8];
    const float* W2    = (const float*)d_in[9];
    const float* as2w  = (const float*)d_in[10];
    const float* ad2w  = (const float*)d_in[11];
    const float* ae2w  = (const float*)d_in[12];
    const float* We2   = (const float*)d_in[13];
    const float* b2    = (const float*)d_in[14];
    const float* g1    = (const float*)d_in[15];
    const float* be1   = (const float*)d_in[16];
    const float* rm1   = (const float*)d_in[17];
    const float* rv1   = (const float*)d_in[18];
    const float* g2    = (const float*)d_in[19];
    const float* be2   = (const float*)d_in[20];
    const float* rm2   = (const float*)d_in[21];
    const float* rv2   = (const float*)d_in[22];

    const int* src0 = ei;
    const int* dst0 = ei + NE;

    char* p = (char*)d_ws;
    auto take = [&](size_t nbytes) {
        void* r = (void*)p;
        p += (nbytes + 255) & ~(size_t)255;
        return r;
    };
    float*    wf1     = (float*)take(80);
    float*    wf2     = (float*)take(20);
    unsigned* w1t     = (unsigned*)take((size_t)128 * 64 * 4);
    unsigned* w2t     = (unsigned*)take((size_t)48 * 64 * 4);
    int*      cnt_rep = (int*)take((size_t)NXCC * NN * 4);
    int*      off     = (int*)take((size_t)(NN + 1) * 4);
    int*      bsum    = (int*)take((size_t)SCAN_NB * 4);
    int*      rpre    = (int*)take((size_t)NN * 8 * 4);
    int*      ctot    = (int*)take((size_t)NN * 4);
    int*      rank    = (int*)take((size_t)NE * 4);
    uint4*    epk     = (uint4*)take((size_t)NE * 16);
    float*    as1     = (float*)take((size_t)NN * 16);
    float*    ad1     = (float*)take((size_t)NN * 16);
    float*    as2     = (float*)take((size_t)NN * 4);
    float*    ad2     = (float*)take((size_t)NN * 4);
    unsigned* xs1u    = (unsigned*)take((size_t)NN * 256);  // 64 uints/row
    unsigned* h1u     = (unsigned*)take((size_t)NN * 256);
    unsigned* xs2u    = (unsigned*)take((size_t)NN * 128);  // 32 uints/row

    prep_kernel<<<SCAN_NB, 256, 0, stream>>>(We1, ae1w, We2, ae2w, W1, W2, wf1, wf2,
                                             w1t, w2t, cnt_rep);
    count_kernel<<<(NE + 1023) / 1024, 256, 0, stream>>>(dst0, cnt_rep, rank);
    gemm1_mfma<<<G1_NB, 256, 0, stream>>>(x, w1t, xs1u);
    scan1_alpha1<<<SCAN_NB + A1_NB, 256, 0, stream>>>(cnt_rep, off, bsum, rpre, ctot,
                                                      xs1u, as1w, ad1w, as1, ad1);
    scan3_kernel<<<SCAN_NB, 256, 0, stream>>>(off, bsum, ctot);
    fill_fold_kernel<<<(NE + 1023) / 1024, 256, 0, stream>>>(src0, dst0, eattr, wf1, wf2,
                                                             off, rank, rpre, epk);
    gat1_kernel<<<NN / 16, 256, 0, stream>>>(epk, off, xs1u, (const float4*)as1,
                                             (const float4*)ad1, b1, g1, be1, rm1, rv1, h1u);
    gemm2_mfma<<<(NN + 63) / 64, 256, 0, stream>>>(h1u, w2t, xs2u);
    alpha2_kernel<<<(NN + 3) / 4, 256, 0, stream>>>(xs2u, as2w, ad2w, as2, ad2);
    gat2_kernel<<<(NN + 3) / 4, 256, 0, stream>>>(epk, off, xs2u, as2, ad2,
                                                  b2, g2, be2, rm2, rv2, (float*)d_out);
}

// Round 16
// 177.480 us; speedup vs baseline: 1.0130x; 1.0130x over previous
//
#include <hip/hip_runtime.h>
#include <hip/hip_bf16.h>

#define NN 50000
#define NE 800000
#define SCAN_NB ((NN + 255) / 256)   // 196 blocks
#define CNT_NB ((NE + 255) / 256)    // 3125 blocks
#define G1_NB ((NN + 63) / 64)       // 782 blocks
#define A1_NB ((NN + 3) / 4)         // 12500 blocks
// IN=128, HID=32, HEADS=4, HC=128, OUT=40, EDIM=5

typedef float f32x4_t __attribute__((ext_vector_type(4)));
typedef float f32x2_t __attribute__((ext_vector_type(2)));
typedef short s16x8_t __attribute__((ext_vector_type(8)));

// bf16 pack/unpack helpers (RNE rounding).
__device__ __forceinline__ unsigned f2bf2(float a, float b) {
    unsigned ua = __float_as_uint(a);
    ua = (ua + 0x7fffu + ((ua >> 16) & 1u)) >> 16;
    unsigned ub = __float_as_uint(b);
    ub = (ub + 0x7fffu + ((ub >> 16) & 1u)) >> 16;
    return ua | (ub << 16);
}
__device__ __forceinline__ float bf_lo(unsigned u) { return __uint_as_float(u << 16); }
__device__ __forceinline__ float bf_hi(unsigned u) { return __uint_as_float(u & 0xffff0000u); }
__device__ __forceinline__ f32x2_t bfpair(unsigned u) {
    return (f32x2_t){__uint_as_float(u << 16), __uint_as_float(u & 0xffff0000u)};
}

// ---------------------------------------------------------------------------
// K0: prep — zero cnt (grid-wide) + folds + bf16-transposed GEMM weights.
__global__ __launch_bounds__(256) void prep_kernel(
    const float* __restrict__ We1, const float* __restrict__ ae1w,
    const float* __restrict__ We2, const float* __restrict__ ae2w,
    const float* __restrict__ W1, const float* __restrict__ W2,
    float* __restrict__ wf1, float* __restrict__ wf2,
    unsigned* __restrict__ w1t, unsigned* __restrict__ w2t,
    int* __restrict__ cnt) {
    int t = threadIdx.x;
    int g = blockIdx.x * 256 + t;
    if (g < NN) cnt[g] = 0;
    if (blockIdx.x != 0) return;
    if (t < 20) {
        int j = t >> 2, h = t & 3;
        float s = 0.f;
        for (int c = 0; c < 32; ++c) s += We1[j * 128 + h * 32 + c] * ae1w[h * 32 + c];
        wf1[j * 4 + h] = s;
    }
    if (t >= 32 && t < 37) {
        int j = t - 32;
        float s = 0.f;
        for (int c = 0; c < 40; ++c) s += We2[j * 40 + c] * ae2w[c];
        wf2[j] = s;
    }
    for (int i = t; i < 128 * 64; i += 256) {
        int c = i >> 6, kp = i & 63;
        w1t[i] = f2bf2(W1[(size_t)(2 * kp) * 128 + c], W1[(size_t)(2 * kp + 1) * 128 + c]);
    }
    for (int i = t; i < 48 * 64; i += 256) {
        int c = i >> 6, kp = i & 63;
        w2t[i] = (c < 40) ? f2bf2(W2[(size_t)(2 * kp) * 40 + c], W2[(size_t)(2 * kp + 1) * 40 + c]) : 0u;
    }
}

// ---------------------------------------------------------------------------
// K1: MERGED [count+rank || MFMA GEMM1] (R12 structure — measured best).
__global__ __launch_bounds__(256) void count_gemm1(
    const int* __restrict__ dst0, int* __restrict__ cnt, int* __restrict__ rank,
    const float* __restrict__ A, const unsigned* __restrict__ w1t,
    unsigned* __restrict__ out) {
    if (blockIdx.x < CNT_NB) {
        int e = blockIdx.x * 256 + threadIdx.x;
        if (e < NE) rank[e] = atomicAdd(&cnt[dst0[e]], 1);
        return;
    }
    __shared__ unsigned sA[64 * 68];
    __shared__ unsigned sB[128 * 68];
    int t = threadIdx.x;
    int row0 = (blockIdx.x - CNT_NB) * 64;
    for (int i = t; i < 64 * 32; i += 256) {
        int r = i >> 5, q = i & 31;
        int gr = row0 + r;
        float4 v = (gr < NN) ? *(const float4*)&A[(size_t)gr * 128 + q * 4]
                             : make_float4(0.f, 0.f, 0.f, 0.f);
        sA[r * 68 + q * 2]     = f2bf2(v.x, v.y);
        sA[r * 68 + q * 2 + 1] = f2bf2(v.z, v.w);
    }
    for (int i = t; i < 128 * 16; i += 256) {
        int c = i >> 4, q = i & 15;
        *(uint4*)&sB[c * 68 + q * 4] = *(const uint4*)&w1t[c * 64 + q * 4];
    }
    __syncthreads();
    int wv = t >> 6, lane = t & 63;
    int lr = lane & 15, kgrp = lane >> 4;
    f32x4_t acc[8];
#pragma unroll
    for (int i = 0; i < 8; ++i) acc[i] = (f32x4_t){0.f, 0.f, 0.f, 0.f};
    int arow = wv * 16 + lr;
#pragma unroll
    for (int kt = 0; kt < 4; ++kt) {
        int kw = kt * 16 + kgrp * 4;
        s16x8_t af = *(const s16x8_t*)&sA[arow * 68 + kw];
#pragma unroll
        for (int tc = 0; tc < 8; ++tc) {
            s16x8_t bf = *(const s16x8_t*)&sB[(tc * 16 + lr) * 68 + kw];
            acc[tc] = __builtin_amdgcn_mfma_f32_16x16x32_bf16(af, bf, acc[tc], 0, 0, 0);
        }
    }
    int orow0 = row0 + wv * 16 + kgrp * 4;
#pragma unroll
    for (int tc = 0; tc < 8; ++tc) {
#pragma unroll
        for (int r = 0; r < 4; ++r) {
            float v = acc[tc][r];
            float other = __shfl_xor(v, 1);
            int gr = orow0 + r;
            if (!(lane & 1) && gr < NN)
                out[(size_t)gr * 64 + tc * 8 + (lr >> 1)] = f2bf2(v, other);
        }
    }
}

// ---------------------------------------------------------------------------
// K2: MERGED [scan1 || alpha1]. bsum gets RAW per-block sums.
__global__ __launch_bounds__(256) void scan1_alpha1(
    const int* __restrict__ cnt, int* __restrict__ off, int* __restrict__ bsum,
    const unsigned* __restrict__ xs1u, const float* __restrict__ asw,
    const float* __restrict__ adw, float* __restrict__ as1, float* __restrict__ ad1) {
    if (blockIdx.x < SCAN_NB) {
        __shared__ int tmp[256];
        int t = threadIdx.x;
        int g = blockIdx.x * 256 + t;
        int v = (g < NN) ? cnt[g] : 0;
        tmp[t] = v;
        __syncthreads();
#pragma unroll
        for (int d = 1; d < 256; d <<= 1) {
            int u = (t >= d) ? tmp[t - d] : 0;
            __syncthreads();
            tmp[t] += u;
            __syncthreads();
        }
        if (g < NN) off[g] = tmp[t] - v;
        if (t == 255) bsum[blockIdx.x] = tmp[255];
        return;
    }
    int wid = ((blockIdx.x - SCAN_NB) * 256 + threadIdx.x) >> 6;
    if (wid >= NN) return;
    int lane = threadIdx.x & 63;
    int c = lane * 2;
    unsigned u = xs1u[(size_t)wid * 64 + lane];
    float vx = bf_lo(u), vy = bf_hi(u);
    float pa = vx * asw[c] + vy * asw[c + 1];
    float pd = vx * adw[c] + vy * adw[c + 1];
#pragma unroll
    for (int d = 8; d >= 1; d >>= 1) {
        pa += __shfl_xor(pa, d, 16);
        pd += __shfl_xor(pd, d, 16);
    }
    if ((lane & 15) == 0) {
        as1[wid * 4 + (lane >> 4)] = pa;
        ad1[wid * 4 + (lane >> 4)] = pd;
    }
}

// ---------------------------------------------------------------------------
// K3: scan finalize — each block redundantly scans the 196 raw block sums.
__global__ __launch_bounds__(256) void scan3_kernel(int* __restrict__ off,
                                                    const int* __restrict__ bsum,
                                                    const int* __restrict__ cnt) {
    __shared__ int tmp[256];
    int t = threadIdx.x;
    int v = (t < SCAN_NB) ? bsum[t] : 0;
    tmp[t] = v;
    __syncthreads();
#pragma unroll
    for (int d = 1; d < 256; d <<= 1) {
        int u = (t >= d) ? tmp[t - d] : 0;
        __syncthreads();
        tmp[t] += u;
        __syncthreads();
    }
    int pre = (blockIdx.x == 0) ? 0 : tmp[blockIdx.x - 1];
    int g = blockIdx.x * 256 + t;
    if (g < NN) {
        int o = off[g] + pre;
        off[g] = o;
        if (g == NN - 1) off[NN] = o + cnt[g];
    }
}

// ---------------------------------------------------------------------------
// K4: fill CSR, atomic-free. 32B record per edge (one 64B sector either way):
//   q0 = {src, (as1[src]+ae1) bf16x4, ae2 fp32}   — gat1 weight phase + gat2
//   q1 = {raw ae1 bf16x4, 0, 0}                   — gat1 self-loop mean
// The random as1[src] gather moves HERE (latency hides under posted stores),
// removing it from gat1's critical loop.
__global__ __launch_bounds__(256) void fill_fold_kernel(
    const int* __restrict__ src0, const int* __restrict__ dst0,
    const float* __restrict__ eattr, const float* __restrict__ wf1,
    const float* __restrict__ wf2, const int* __restrict__ off,
    const int* __restrict__ rank, const float4* __restrict__ as1v,
    uint4* __restrict__ epk2) {
    int base = blockIdx.x * 1024 + threadIdx.x;
#pragma unroll
    for (int k = 0; k < 4; ++k) {
        int e = base + k * 256;
        if (e >= NE) continue;
        float a[5];
#pragma unroll
        for (int j = 0; j < 5; ++j) a[j] = eattr[(size_t)e * 5 + j];
        float o[4];
#pragma unroll
        for (int h = 0; h < 4; ++h) {
            float s = 0.f;
#pragma unroll
            for (int j = 0; j < 5; ++j) s += a[j] * wf1[j * 4 + h];
            o[h] = s;
        }
        float s2 = 0.f;
#pragma unroll
        for (int j = 0; j < 5; ++j) s2 += a[j] * wf2[j];
        int sv = src0[e];
        float4 av = as1v[sv];
        int pos = off[dst0[e]] + rank[e];
        epk2[(size_t)pos * 2] = make_uint4((unsigned)sv,
                                           f2bf2(av.x + o[0], av.y + o[1]),
                                           f2bf2(av.z + o[2], av.w + o[3]),
                                           __float_as_uint(s2));
        epk2[(size_t)pos * 2 + 1] = make_uint4(f2bf2(o[0], o[1]), f2bf2(o[2], o[3]), 0u, 0u);
    }
}

// ---------------------------------------------------------------------------
// K5: layer-1 GAT aggregation. 4 nodes/wave, 16 lanes/node. Weight phase has
// NO random gathers (as1[src] pre-combined into the record).
__global__ __launch_bounds__(256) void gat1_kernel(
    const uint4* __restrict__ epk2, const int* __restrict__ off,
    const unsigned* __restrict__ xs1u,
    const float4* __restrict__ as1, const float4* __restrict__ ad1,
    const float* __restrict__ b1, const float* __restrict__ g1, const float* __restrict__ be1,
    const float* __restrict__ rm1, const float* __restrict__ rv1, unsigned* __restrict__ h1u) {
    __shared__ int   lds_s[4][4][16];
    __shared__ float lds_w[4][4][16][4];
    int wave = threadIdx.x >> 6;
    int lane = threadIdx.x & 63;
    int g = lane >> 4;
    int lr = lane & 15;
    int qh = lr >> 2;
    int n = blockIdx.x * 16 + wave * 4 + g;
    int e0 = off[n];
    int deg = off[n + 1] - e0;
    float4 adn = ad1[n];
    float4 asn = as1[n];
    f32x2_t acc2[4];
#pragma unroll
    for (int k = 0; k < 4; ++k) acc2[k] = (f32x2_t){0.f, 0.f};
    float ds0 = 0.f, ds1 = 0.f, ds2 = 0.f, ds3 = 0.f;
    float s0 = 0.f, s1 = 0.f, s2 = 0.f, s3 = 0.f;
    int mc = (deg + 15) >> 4;
    mc = max(mc, __shfl_xor(mc, 16));
    mc = max(mc, __shfl_xor(mc, 32));

    for (int ch = 0; ch < mc; ++ch) {
        int i = ch * 16 + lr;
        int s = 0;
        float w0 = 0.f, w1 = 0.f, w2 = 0.f, w3 = 0.f;
        if (i < deg) {
            uint4 q0 = epk2[(size_t)(e0 + i) * 2];
            uint4 q1 = epk2[(size_t)(e0 + i) * 2 + 1];
            s = (int)q0.x;
            float a0 = bf_lo(q0.y) + adn.x;
            float a1 = bf_hi(q0.y) + adn.y;
            float a2 = bf_lo(q0.z) + adn.z;
            float a3 = bf_hi(q0.z) + adn.w;
            a0 = a0 >= 0.f ? a0 : 0.2f * a0;
            a1 = a1 >= 0.f ? a1 : 0.2f * a1;
            a2 = a2 >= 0.f ? a2 : 0.2f * a2;
            a3 = a3 >= 0.f ? a3 : 0.2f * a3;
            w0 = __expf(a0); w1 = __expf(a1); w2 = __expf(a2); w3 = __expf(a3);
            ds0 += w0; ds1 += w1; ds2 += w2; ds3 += w3;
            s0 += bf_lo(q1.x); s1 += bf_hi(q1.x);
            s2 += bf_lo(q1.y); s3 += bf_hi(q1.y);
        }
        lds_s[wave][g][lr] = s;
        *(float4*)&lds_w[wave][g][lr][0] = make_float4(w0, w1, w2, w3);
        __builtin_amdgcn_wave_barrier();
        int cn = deg - ch * 16;
        cn = cn > 16 ? 16 : (cn < 0 ? 0 : cn);
        int cnr = (cn + 3) & ~3;
        for (int j = 0; j < cnr; j += 4) {
            int sj0 = lds_s[wave][g][j];
            int sj1 = lds_s[wave][g][j + 1];
            int sj2 = lds_s[wave][g][j + 2];
            int sj3 = lds_s[wave][g][j + 3];
            float ww0 = lds_w[wave][g][j][qh];
            float ww1 = lds_w[wave][g][j + 1][qh];
            float ww2 = lds_w[wave][g][j + 2][qh];
            float ww3 = lds_w[wave][g][j + 3][qh];
            uint4 u0 = *(const uint4*)&xs1u[(size_t)sj0 * 64 + lr * 4];
            uint4 u1 = *(const uint4*)&xs1u[(size_t)sj1 * 64 + lr * 4];
            uint4 u2 = *(const uint4*)&xs1u[(size_t)sj2 * 64 + lr * 4];
            uint4 u3 = *(const uint4*)&xs1u[(size_t)sj3 * 64 + lr * 4];
            f32x2_t W0 = {ww0, ww0}, W1v = {ww1, ww1}, W2v = {ww2, ww2}, W3v = {ww3, ww3};
            acc2[0] += W0 * bfpair(u0.x); acc2[1] += W0 * bfpair(u0.y);
            acc2[2] += W0 * bfpair(u0.z); acc2[3] += W0 * bfpair(u0.w);
            acc2[0] += W1v * bfpair(u1.x); acc2[1] += W1v * bfpair(u1.y);
            acc2[2] += W1v * bfpair(u1.z); acc2[3] += W1v * bfpair(u1.w);
            acc2[0] += W2v * bfpair(u2.x); acc2[1] += W2v * bfpair(u2.y);
            acc2[2] += W2v * bfpair(u2.z); acc2[3] += W2v * bfpair(u2.w);
            acc2[0] += W3v * bfpair(u3.x); acc2[1] += W3v * bfpair(u3.y);
            acc2[2] += W3v * bfpair(u3.z); acc2[3] += W3v * bfpair(u3.w);
        }
        __builtin_amdgcn_wave_barrier();
    }
#pragma unroll
    for (int d = 8; d >= 1; d >>= 1) {
        ds0 += __shfl_xor(ds0, d, 16); ds1 += __shfl_xor(ds1, d, 16);
        ds2 += __shfl_xor(ds2, d, 16); ds3 += __shfl_xor(ds3, d, 16);
        s0 += __shfl_xor(s0, d, 16);   s1 += __shfl_xor(s1, d, 16);
        s2 += __shfl_xor(s2, d, 16);   s3 += __shfl_xor(s3, d, 16);
    }
    float invd = 1.f / fmaxf((float)deg, 1.f);
    float aL0 = asn.x + adn.x + s0 * invd;
    float aL1 = asn.y + adn.y + s1 * invd;
    float aL2 = asn.z + adn.z + s2 * invd;
    float aL3 = asn.w + adn.w + s3 * invd;
    aL0 = aL0 >= 0.f ? aL0 : 0.2f * aL0;
    aL1 = aL1 >= 0.f ? aL1 : 0.2f * aL1;
    aL2 = aL2 >= 0.f ? aL2 : 0.2f * aL2;
    aL3 = aL3 >= 0.f ? aL3 : 0.2f * aL3;
    float ws0 = __expf(aL0), ws1 = __expf(aL1), ws2 = __expf(aL2), ws3 = __expf(aL3);
    float wself = qh == 0 ? ws0 : (qh == 1 ? ws1 : (qh == 2 ? ws2 : ws3));
    float dh = qh == 0 ? ds0 + ws0 : (qh == 1 ? ds1 + ws1 : (qh == 2 ? ds2 + ws2 : ds3 + ws3));
    uint4 us = *(const uint4*)&xs1u[(size_t)n * 64 + lr * 4];
    f32x2_t Ws = {wself, wself};
    acc2[0] += Ws * bfpair(us.x); acc2[1] += Ws * bfpair(us.y);
    acc2[2] += Ws * bfpair(us.z); acc2[3] += Ws * bfpair(us.w);
    float inv = 1.f / (dh + 1e-16f);
    int c = lr * 8;
    uint4 ou;
    unsigned* op = (unsigned*)&ou;
#pragma unroll
    for (int k2 = 0; k2 < 4; ++k2) {
        int c0 = c + 2 * k2, c1 = c + 2 * k2 + 1;
        float o0 = acc2[k2][0] * inv + b1[c0];
        float o1 = acc2[k2][1] * inv + b1[c1];
        float sc0 = g1[c0] * rsqrtf(rv1[c0] + 1e-5f);
        float sc1 = g1[c1] * rsqrtf(rv1[c1] + 1e-5f);
        o0 = (o0 - rm1[c0]) * sc0 + be1[c0];
        o1 = (o1 - rm1[c1]) * sc1 + be1[c1];
        o0 = o0 > 0.f ? o0 : __expf(o0) - 1.f;
        o1 = o1 > 0.f ? o1 : __expf(o1) - 1.f;
        op[k2] = f2bf2(o0, o1);
    }
    *(uint4*)&h1u[(size_t)n * 64 + lr * 4] = ou;
}

// ---------------------------------------------------------------------------
// K6: MFMA GEMM2: xs2[N,40](bf16, stride 64) = h1(bf16) @ W2(bf16,48-pad).
__global__ __launch_bounds__(256) void gemm2_mfma(
    const unsigned* __restrict__ A, const unsigned* __restrict__ w2t,
    unsigned* __restrict__ out) {
    __shared__ unsigned sA[64 * 68];
    __shared__ unsigned sB[48 * 68];
    int t = threadIdx.x;
    int row0 = blockIdx.x * 64;
    for (int i = t; i < 64 * 16; i += 256) {
        int r = i >> 4, q = i & 15;
        int gr = row0 + r;
        uint4 v = (gr < NN) ? *(const uint4*)&A[(size_t)gr * 64 + q * 4]
                            : make_uint4(0u, 0u, 0u, 0u);
        *(uint4*)&sA[r * 68 + q * 4] = v;
    }
    for (int i = t; i < 48 * 16; i += 256) {
        int c = i >> 4, q = i & 15;
        *(uint4*)&sB[c * 68 + q * 4] = *(const uint4*)&w2t[c * 64 + q * 4];
    }
    __syncthreads();
    int wv = t >> 6, lane = t & 63;
    int lr = lane & 15, kgrp = lane >> 4;
    f32x4_t acc[3];
#pragma unroll
    for (int i = 0; i < 3; ++i) acc[i] = (f32x4_t){0.f, 0.f, 0.f, 0.f};
    int arow = wv * 16 + lr;
#pragma unroll
    for (int kt = 0; kt < 4; ++kt) {
        int kw = kt * 16 + kgrp * 4;
        s16x8_t af = *(const s16x8_t*)&sA[arow * 68 + kw];
#pragma unroll
        for (int tc = 0; tc < 3; ++tc) {
            s16x8_t bf = *(const s16x8_t*)&sB[(tc * 16 + lr) * 68 + kw];
            acc[tc] = __builtin_amdgcn_mfma_f32_16x16x32_bf16(af, bf, acc[tc], 0, 0, 0);
        }
    }
    int orow0 = row0 + wv * 16 + kgrp * 4;
#pragma unroll
    for (int tc = 0; tc < 3; ++tc) {
#pragma unroll
        for (int r = 0; r < 4; ++r) {
            float v = acc[tc][r];
            float other = __shfl_xor(v, 1);
            int gr = orow0 + r;
            if (!(lane & 1) && gr < NN && (tc < 2 || lr < 8))
                out[(size_t)gr * 32 + tc * 8 + (lr >> 1)] = f2bf2(v, other);
        }
    }
}

// ---------------------------------------------------------------------------
// K7: per-node attention coefficients layer 2 (from bf16 xs2).
__global__ __launch_bounds__(256) void alpha2_kernel(
    const unsigned* __restrict__ xs2u, const float* __restrict__ asw,
    const float* __restrict__ adw, float* __restrict__ as2, float* __restrict__ ad2) {
    int wid = (blockIdx.x * 256 + threadIdx.x) >> 6;
    if (wid >= NN) return;
    int lane = threadIdx.x & 63;
    float pa = 0.f, pd = 0.f;
    if (lane < 20) {
        unsigned u = xs2u[(size_t)wid * 32 + lane];
        float vx = bf_lo(u), vy = bf_hi(u);
        int c = lane * 2;
        pa = vx * asw[c] + vy * asw[c + 1];
        pd = vx * adw[c] + vy * adw[c + 1];
    }
#pragma unroll
    for (int d = 16; d >= 1; d >>= 1) {
        pa += __shfl_xor(pa, d, 32);
        pd += __shfl_xor(pd, d, 32);
    }
    if (lane == 0) { as2[wid] = pa; ad2[wid] = pd; }
}

// ---------------------------------------------------------------------------
// K8: layer-2 GAT aggregation + bias + BN + log_softmax. Reads record q0 only
// (stride-2 uint4).
__global__ __launch_bounds__(256) void gat2_kernel(
    const uint4* __restrict__ epk2, const int* __restrict__ off,
    const unsigned* __restrict__ xs2u,
    const float* __restrict__ as2, const float* __restrict__ ad2,
    const float* __restrict__ b2, const float* __restrict__ g2, const float* __restrict__ be2,
    const float* __restrict__ rm2, const float* __restrict__ rv2, float* __restrict__ outp) {
    __shared__ int   lds_s[4][72];
    __shared__ float lds_w[4][72];
    int wid = (blockIdx.x * 256 + threadIdx.x) >> 6;
    if (wid >= NN) return;
    int lane = threadIdx.x & 63;
    int warp = threadIdx.x >> 6;
    int n = wid;
    int e0 = off[n], e1 = off[n + 1];
    int deg = e1 - e0;
    int grp3 = lane / 20;
    int col = lane - grp3 * 20;
    bool act = grp3 < 3;
    int grpo = act ? grp3 : 0;
    if (lane < 8) {
        lds_s[warp][64 + lane] = 0;
        lds_w[warp][64 + lane] = 0.f;
    }
    float adn = ad2[n];
    float asn = as2[n];
    f32x2_t acc2 = {0.f, 0.f};
    float dsum = 0.f, aesum = 0.f;

    for (int base = 0; base < deg; base += 64) {
        int i = base + lane;
        int cn = min(64, deg - base);
        int s = 0;
        float w = 0.f;
        if (i < deg) {
            uint4 ep = epk2[(size_t)(e0 + i) * 2];
            s = (int)ep.x;
            float ae = __uint_as_float(ep.w);
            float a = as2[s] + adn + ae;
            a = a >= 0.f ? a : 0.2f * a;
            w = __expf(a);
            dsum += w;
            aesum += ae;
        }
        lds_s[warp][lane] = s;
        lds_w[warp][lane] = w;
        __builtin_amdgcn_wave_barrier();
        int cnr = ((cn + 11) / 12) * 12;            // <= 72; jj max = 71
        for (int j = 0; j < cnr; j += 12) {
            int jj0 = j + grpo, jj1 = jj0 + 3, jj2 = jj0 + 6, jj3 = jj0 + 9;
            int sj0 = lds_s[warp][jj0];
            int sj1 = lds_s[warp][jj1];
            int sj2 = lds_s[warp][jj2];
            int sj3 = lds_s[warp][jj3];
            float w0 = act ? lds_w[warp][jj0] : 0.f;
            float w1 = act ? lds_w[warp][jj1] : 0.f;
            float w2 = act ? lds_w[warp][jj2] : 0.f;
            float w3 = act ? lds_w[warp][jj3] : 0.f;
            unsigned u0 = xs2u[(size_t)sj0 * 32 + col];
            unsigned u1 = xs2u[(size_t)sj1 * 32 + col];
            unsigned u2 = xs2u[(size_t)sj2 * 32 + col];
            unsigned u3 = xs2u[(size_t)sj3 * 32 + col];
            acc2 += (f32x2_t){w0, w0} * bfpair(u0);
            acc2 += (f32x2_t){w1, w1} * bfpair(u1);
            acc2 += (f32x2_t){w2, w2} * bfpair(u2);
            acc2 += (f32x2_t){w3, w3} * bfpair(u3);
        }
        __builtin_amdgcn_wave_barrier();
    }
    {
        float p0 = __shfl(acc2[0], (lane + 20) & 63);
        float p1 = __shfl(acc2[1], (lane + 20) & 63);
        float q0 = __shfl(acc2[0], (lane + 40) & 63);
        float q1 = __shfl(acc2[1], (lane + 40) & 63);
        acc2[0] += p0 + q0;
        acc2[1] += p1 + q1;
    }
#pragma unroll
    for (int d = 32; d >= 1; d >>= 1) {
        dsum += __shfl_xor(dsum, d);
        aesum += __shfl_xor(aesum, d);
    }
    float invd = 1.f / fmaxf((float)deg, 1.f);
    float aL = asn + adn + aesum * invd;
    aL = aL >= 0.f ? aL : 0.2f * aL;
    float wself = __expf(aL);
    float denom = dsum + wself;

    float v0 = 0.f, v1 = 0.f;
    if (lane < 20) {
        unsigned u = xs2u[(size_t)n * 32 + lane];
        acc2[0] += wself * bf_lo(u);
        acc2[1] += wself * bf_hi(u);
        int c = lane * 2;
        float inv = 1.f / (denom + 1e-16f);
        v0 = acc2[0] * inv + b2[c];
        v1 = acc2[1] * inv + b2[c + 1];
        float sc0 = g2[c] * rsqrtf(rv2[c] + 1e-5f);
        float sc1 = g2[c + 1] * rsqrtf(rv2[c + 1] + 1e-5f);
        v0 = (v0 - rm2[c]) * sc0 + be2[c];
        v1 = (v1 - rm2[c + 1]) * sc1 + be2[c + 1];
    }
    float mx = (lane < 20) ? fmaxf(v0, v1) : -3.0e38f;
#pragma unroll
    for (int d = 32; d >= 1; d >>= 1) mx = fmaxf(mx, __shfl_xor(mx, d));
    float ex = (lane < 20) ? __expf(v0 - mx) + __expf(v1 - mx) : 0.f;
#pragma unroll
    for (int d = 32; d >= 1; d >>= 1) ex += __shfl_xor(ex, d);
    if (lane < 20) {
        float ls = __logf(ex);
        *(float2*)&outp[(size_t)n * 40 + lane * 2] = make_float2(v0 - mx - ls, v1 - mx - ls);
    }
}

// ---------------------------------------------------------------------------
extern "C" void kernel_launch(void* const* d_in, const int* in_sizes, int n_in,
                              void* d_out, int out_size, void* d_ws, size_t ws_size,
                              hipStream_t stream) {
    const float* x     = (const float*)d_in[0];
    const int*   ei    = (const int*)d_in[1];
    const float* eattr = (const float*)d_in[2];
    const float* W1    = (const float*)d_in[3];
    const float* as1w  = (const float*)d_in[4];
    const float* ad1w  = (const float*)d_in[5];
    const float* ae1w  = (const float*)d_in[6];
    const float* We1   = (const float*)d_in[7];
    const float* b1    = (const float*)d_in[8];
    const float* W2    = (const float*)d_in[9];
    const float* as2w  = (const float*)d_in[10];
    const float* ad2w  = (const float*)d_in[11];
    const float* ae2w  = (const float*)d_in[12];
    const float* We2   = (const float*)d_in[13];
    const float* b2    = (const float*)d_in[14];
    const float* g1    = (const float*)d_in[15];
    const float* be1   = (const float*)d_in[16];
    const float* rm1   = (const float*)d_in[17];
    const float* rv1   = (const float*)d_in[18];
    const float* g2    = (const float*)d_in[19];
    const float* be2   = (const float*)d_in[20];
    const float* rm2   = (const float*)d_in[21];
    const float* rv2   = (const float*)d_in[22];

    const int* src0 = ei;
    const int* dst0 = ei + NE;

    char* p = (char*)d_ws;
    auto take = [&](size_t nbytes) {
        void* r = (void*)p;
        p += (nbytes + 255) & ~(size_t)255;
        return r;
    };
    float*    wf1    = (float*)take(80);
    float*    wf2    = (float*)take(20);
    unsigned* w1t    = (unsigned*)take((size_t)128 * 64 * 4);
    unsigned* w2t    = (unsigned*)take((size_t)48 * 64 * 4);
    int*      cnt    = (int*)take((size_t)NN * 4);
    int*      off    = (int*)take((size_t)(NN + 1) * 4);
    int*      bsum   = (int*)take((size_t)SCAN_NB * 4);
    int*      rank   = (int*)take((size_t)NE * 4);
    uint4*    epk2   = (uint4*)take((size_t)NE * 32);
    float*    as1    = (float*)take((size_t)NN * 16);
    float*    ad1    = (float*)take((size_t)NN * 16);
    float*    as2    = (float*)take((size_t)NN * 4);
    float*    ad2    = (float*)take((size_t)NN * 4);
    unsigned* xs1u   = (unsigned*)take((size_t)NN * 256);  // 64 uints/row
    unsigned* h1u    = (unsigned*)take((size_t)NN * 256);
    unsigned* xs2u   = (unsigned*)take((size_t)NN * 128);  // 32 uints/row

    prep_kernel<<<SCAN_NB, 256, 0, stream>>>(We1, ae1w, We2, ae2w, W1, W2, wf1, wf2,
                                             w1t, w2t, cnt);
    count_gemm1<<<CNT_NB + G1_NB, 256, 0, stream>>>(dst0, cnt, rank, x, w1t, xs1u);
    scan1_alpha1<<<SCAN_NB + A1_NB, 256, 0, stream>>>(cnt, off, bsum, xs1u, as1w, ad1w,
                                                      as1, ad1);
    scan3_kernel<<<SCAN_NB, 256, 0, stream>>>(off, bsum, cnt);
    fill_fold_kernel<<<(NE + 1023) / 1024, 256, 0, stream>>>(src0, dst0, eattr, wf1, wf2,
                                                             off, rank, (const float4*)as1,
                                                             epk2);
    gat1_kernel<<<NN / 16, 256, 0, stream>>>(epk2, off, xs1u, (const float4*)as1,
                                             (const float4*)ad1, b1, g1, be1, rm1, rv1, h1u);
    gemm2_mfma<<<(NN + 63) / 64, 256, 0, stream>>>(h1u, w2t, xs2u);
    alpha2_kernel<<<(NN + 3) / 4, 256, 0, stream>>>(xs2u, as2w, ad2w, as2, ad2);
    gat2_kernel<<<(NN + 3) / 4, 256, 0, stream>>>(epk2, off, xs2u, as2, ad2,
                                                  b2, g2, be2, rm2, rv2, (float*)d_out);
}

// Round 17
// 166.052 us; speedup vs baseline: 1.0828x; 1.0688x over previous
//
#include <hip/hip_runtime.h>
#include <hip/hip_bf16.h>

#define NN 50000
#define NE 800000
#define SCAN_NB ((NN + 255) / 256)   // 196 blocks
#define CNT_NB ((NE + 255) / 256)    // 3125 blocks
#define G1_NB ((NN + 63) / 64)       // 782 blocks
#define A1_NB ((NN + 3) / 4)         // 12500 blocks
// IN=128, HID=32, HEADS=4, HC=128, OUT=40, EDIM=5

typedef float f32x4_t __attribute__((ext_vector_type(4)));
typedef float f32x2_t __attribute__((ext_vector_type(2)));
typedef short s16x8_t __attribute__((ext_vector_type(8)));

// bf16 pack/unpack helpers (RNE rounding).
__device__ __forceinline__ unsigned f2bf2(float a, float b) {
    unsigned ua = __float_as_uint(a);
    ua = (ua + 0x7fffu + ((ua >> 16) & 1u)) >> 16;
    unsigned ub = __float_as_uint(b);
    ub = (ub + 0x7fffu + ((ub >> 16) & 1u)) >> 16;
    return ua | (ub << 16);
}
__device__ __forceinline__ float bf_lo(unsigned u) { return __uint_as_float(u << 16); }
__device__ __forceinline__ float bf_hi(unsigned u) { return __uint_as_float(u & 0xffff0000u); }
__device__ __forceinline__ f32x2_t bfpair(unsigned u) {
    return (f32x2_t){__uint_as_float(u << 16), __uint_as_float(u & 0xffff0000u)};
}

// ---------------------------------------------------------------------------
// K0: prep — zero cnt (grid-wide) + folds + bf16-transposed GEMM weights.
__global__ __launch_bounds__(256) void prep_kernel(
    const float* __restrict__ We1, const float* __restrict__ ae1w,
    const float* __restrict__ We2, const float* __restrict__ ae2w,
    const float* __restrict__ W1, const float* __restrict__ W2,
    float* __restrict__ wf1, float* __restrict__ wf2,
    unsigned* __restrict__ w1t, unsigned* __restrict__ w2t,
    int* __restrict__ cnt) {
    int t = threadIdx.x;
    int g = blockIdx.x * 256 + t;
    if (g < NN) cnt[g] = 0;
    if (blockIdx.x != 0) return;
    if (t < 20) {
        int j = t >> 2, h = t & 3;
        float s = 0.f;
        for (int c = 0; c < 32; ++c) s += We1[j * 128 + h * 32 + c] * ae1w[h * 32 + c];
        wf1[j * 4 + h] = s;
    }
    if (t >= 32 && t < 37) {
        int j = t - 32;
        float s = 0.f;
        for (int c = 0; c < 40; ++c) s += We2[j * 40 + c] * ae2w[c];
        wf2[j] = s;
    }
    for (int i = t; i < 128 * 64; i += 256) {
        int c = i >> 6, kp = i & 63;
        w1t[i] = f2bf2(W1[(size_t)(2 * kp) * 128 + c], W1[(size_t)(2 * kp + 1) * 128 + c]);
    }
    for (int i = t; i < 48 * 64; i += 256) {
        int c = i >> 6, kp = i & 63;
        w2t[i] = (c < 40) ? f2bf2(W2[(size_t)(2 * kp) * 40 + c], W2[(size_t)(2 * kp + 1) * 40 + c]) : 0u;
    }
}

// ---------------------------------------------------------------------------
// K1: MERGED [count+rank || MFMA GEMM1] (R12 structure — measured best).
__global__ __launch_bounds__(256) void count_gemm1(
    const int* __restrict__ dst0, int* __restrict__ cnt, int* __restrict__ rank,
    const float* __restrict__ A, const unsigned* __restrict__ w1t,
    unsigned* __restrict__ out) {
    if (blockIdx.x < CNT_NB) {
        int e = blockIdx.x * 256 + threadIdx.x;
        if (e < NE) rank[e] = atomicAdd(&cnt[dst0[e]], 1);
        return;
    }
    __shared__ unsigned sA[64 * 68];
    __shared__ unsigned sB[128 * 68];
    int t = threadIdx.x;
    int row0 = (blockIdx.x - CNT_NB) * 64;
    for (int i = t; i < 64 * 32; i += 256) {
        int r = i >> 5, q = i & 31;
        int gr = row0 + r;
        float4 v = (gr < NN) ? *(const float4*)&A[(size_t)gr * 128 + q * 4]
                             : make_float4(0.f, 0.f, 0.f, 0.f);
        sA[r * 68 + q * 2]     = f2bf2(v.x, v.y);
        sA[r * 68 + q * 2 + 1] = f2bf2(v.z, v.w);
    }
    for (int i = t; i < 128 * 16; i += 256) {
        int c = i >> 4, q = i & 15;
        *(uint4*)&sB[c * 68 + q * 4] = *(const uint4*)&w1t[c * 64 + q * 4];
    }
    __syncthreads();
    int wv = t >> 6, lane = t & 63;
    int lr = lane & 15, kgrp = lane >> 4;
    f32x4_t acc[8];
#pragma unroll
    for (int i = 0; i < 8; ++i) acc[i] = (f32x4_t){0.f, 0.f, 0.f, 0.f};
    int arow = wv * 16 + lr;
#pragma unroll
    for (int kt = 0; kt < 4; ++kt) {
        int kw = kt * 16 + kgrp * 4;
        s16x8_t af = *(const s16x8_t*)&sA[arow * 68 + kw];
#pragma unroll
        for (int tc = 0; tc < 8; ++tc) {
            s16x8_t bf = *(const s16x8_t*)&sB[(tc * 16 + lr) * 68 + kw];
            acc[tc] = __builtin_amdgcn_mfma_f32_16x16x32_bf16(af, bf, acc[tc], 0, 0, 0);
        }
    }
    int orow0 = row0 + wv * 16 + kgrp * 4;
#pragma unroll
    for (int tc = 0; tc < 8; ++tc) {
#pragma unroll
        for (int r = 0; r < 4; ++r) {
            float v = acc[tc][r];
            float other = __shfl_xor(v, 1);
            int gr = orow0 + r;
            if (!(lane & 1) && gr < NN)
                out[(size_t)gr * 64 + tc * 8 + (lr >> 1)] = f2bf2(v, other);
        }
    }
}

// ---------------------------------------------------------------------------
// K2: MERGED [scan1 || alpha1]. bsum gets RAW per-block sums.
__global__ __launch_bounds__(256) void scan1_alpha1(
    const int* __restrict__ cnt, int* __restrict__ off, int* __restrict__ bsum,
    const unsigned* __restrict__ xs1u, const float* __restrict__ asw,
    const float* __restrict__ adw, float* __restrict__ as1, float* __restrict__ ad1) {
    if (blockIdx.x < SCAN_NB) {
        __shared__ int tmp[256];
        int t = threadIdx.x;
        int g = blockIdx.x * 256 + t;
        int v = (g < NN) ? cnt[g] : 0;
        tmp[t] = v;
        __syncthreads();
#pragma unroll
        for (int d = 1; d < 256; d <<= 1) {
            int u = (t >= d) ? tmp[t - d] : 0;
            __syncthreads();
            tmp[t] += u;
            __syncthreads();
        }
        if (g < NN) off[g] = tmp[t] - v;
        if (t == 255) bsum[blockIdx.x] = tmp[255];
        return;
    }
    int wid = ((blockIdx.x - SCAN_NB) * 256 + threadIdx.x) >> 6;
    if (wid >= NN) return;
    int lane = threadIdx.x & 63;
    int c = lane * 2;
    unsigned u = xs1u[(size_t)wid * 64 + lane];
    float vx = bf_lo(u), vy = bf_hi(u);
    float pa = vx * asw[c] + vy * asw[c + 1];
    float pd = vx * adw[c] + vy * adw[c + 1];
#pragma unroll
    for (int d = 8; d >= 1; d >>= 1) {
        pa += __shfl_xor(pa, d, 16);
        pd += __shfl_xor(pd, d, 16);
    }
    if ((lane & 15) == 0) {
        as1[wid * 4 + (lane >> 4)] = pa;
        ad1[wid * 4 + (lane >> 4)] = pd;
    }
}

// ---------------------------------------------------------------------------
// K3: scan finalize — each block redundantly scans the 196 raw block sums.
__global__ __launch_bounds__(256) void scan3_kernel(int* __restrict__ off,
                                                    const int* __restrict__ bsum,
                                                    const int* __restrict__ cnt) {
    __shared__ int tmp[256];
    int t = threadIdx.x;
    int v = (t < SCAN_NB) ? bsum[t] : 0;
    tmp[t] = v;
    __syncthreads();
#pragma unroll
    for (int d = 1; d < 256; d <<= 1) {
        int u = (t >= d) ? tmp[t - d] : 0;
        __syncthreads();
        tmp[t] += u;
        __syncthreads();
    }
    int pre = (blockIdx.x == 0) ? 0 : tmp[blockIdx.x - 1];
    int g = blockIdx.x * 256 + t;
    if (g < NN) {
        int o = off[g] + pre;
        off[g] = o;
        if (g == NN - 1) off[NN] = o + cnt[g];
    }
}

// ---------------------------------------------------------------------------
// K4: fill CSR in slot order, atomic-free (pos = off[dst] + rank).
__global__ __launch_bounds__(256) void fill_fold_kernel(
    const int* __restrict__ src0, const int* __restrict__ dst0,
    const float* __restrict__ eattr, const float* __restrict__ wf1,
    const float* __restrict__ wf2, const int* __restrict__ off,
    const int* __restrict__ rank, uint4* __restrict__ epk) {
    int base = blockIdx.x * 1024 + threadIdx.x;
#pragma unroll
    for (int k = 0; k < 4; ++k) {
        int e = base + k * 256;
        if (e >= NE) continue;
        float a[5];
#pragma unroll
        for (int j = 0; j < 5; ++j) a[j] = eattr[(size_t)e * 5 + j];
        float o[4];
#pragma unroll
        for (int h = 0; h < 4; ++h) {
            float s = 0.f;
#pragma unroll
            for (int j = 0; j < 5; ++j) s += a[j] * wf1[j * 4 + h];
            o[h] = s;
        }
        float s2 = 0.f;
#pragma unroll
        for (int j = 0; j < 5; ++j) s2 += a[j] * wf2[j];
        int pos = off[dst0[e]] + rank[e];
        epk[pos] = make_uint4((unsigned)src0[e], f2bf2(o[0], o[1]), f2bf2(o[2], o[3]),
                              __float_as_uint(s2));
    }
}

// ---------------------------------------------------------------------------
// K5: layer-1 GAT aggregation. 4 nodes/wave, 16 lanes/node.
__global__ __launch_bounds__(256) void gat1_kernel(
    const uint4* __restrict__ epk, const int* __restrict__ off,
    const unsigned* __restrict__ xs1u,
    const float4* __restrict__ as1, const float4* __restrict__ ad1,
    const float* __restrict__ b1, const float* __restrict__ g1, const float* __restrict__ be1,
    const float* __restrict__ rm1, const float* __restrict__ rv1, unsigned* __restrict__ h1u) {
    __shared__ int   lds_s[4][4][16];
    __shared__ float lds_w[4][4][16][4];
    int wave = threadIdx.x >> 6;
    int lane = threadIdx.x & 63;
    int g = lane >> 4;
    int lr = lane & 15;
    int qh = lr >> 2;
    int n = blockIdx.x * 16 + wave * 4 + g;
    int e0 = off[n];
    int deg = off[n + 1] - e0;
    float4 adn = ad1[n];
    float4 asn = as1[n];
    f32x2_t acc2[4];
#pragma unroll
    for (int k = 0; k < 4; ++k) acc2[k] = (f32x2_t){0.f, 0.f};
    float ds0 = 0.f, ds1 = 0.f, ds2 = 0.f, ds3 = 0.f;
    float s0 = 0.f, s1 = 0.f, s2 = 0.f, s3 = 0.f;
    int mc = (deg + 15) >> 4;
    mc = max(mc, __shfl_xor(mc, 16));
    mc = max(mc, __shfl_xor(mc, 32));

    for (int ch = 0; ch < mc; ++ch) {
        int i = ch * 16 + lr;
        int s = 0;
        float w0 = 0.f, w1 = 0.f, w2 = 0.f, w3 = 0.f;
        if (i < deg) {
            uint4 ep = epk[e0 + i];
            s = (int)ep.x;
            float ax = bf_lo(ep.y), ay = bf_hi(ep.y);
            float az = bf_lo(ep.z), aw = bf_hi(ep.z);
            float4 av = as1[s];
            float a0 = av.x + adn.x + ax;
            float a1 = av.y + adn.y + ay;
            float a2 = av.z + adn.z + az;
            float a3 = av.w + adn.w + aw;
            a0 = a0 >= 0.f ? a0 : 0.2f * a0;
            a1 = a1 >= 0.f ? a1 : 0.2f * a1;
            a2 = a2 >= 0.f ? a2 : 0.2f * a2;
            a3 = a3 >= 0.f ? a3 : 0.2f * a3;
            w0 = __expf(a0); w1 = __expf(a1); w2 = __expf(a2); w3 = __expf(a3);
            ds0 += w0; ds1 += w1; ds2 += w2; ds3 += w3;
            s0 += ax; s1 += ay; s2 += az; s3 += aw;
        }
        lds_s[wave][g][lr] = s;
        *(float4*)&lds_w[wave][g][lr][0] = make_float4(w0, w1, w2, w3);
        __builtin_amdgcn_wave_barrier();
        int cn = deg - ch * 16;
        cn = cn > 16 ? 16 : (cn < 0 ? 0 : cn);
        int cnr = (cn + 3) & ~3;
        for (int j = 0; j < cnr; j += 4) {
            int sj0 = lds_s[wave][g][j];
            int sj1 = lds_s[wave][g][j + 1];
            int sj2 = lds_s[wave][g][j + 2];
            int sj3 = lds_s[wave][g][j + 3];
            float ww0 = lds_w[wave][g][j][qh];
            float ww1 = lds_w[wave][g][j + 1][qh];
            float ww2 = lds_w[wave][g][j + 2][qh];
            float ww3 = lds_w[wave][g][j + 3][qh];
            uint4 u0 = *(const uint4*)&xs1u[(size_t)sj0 * 64 + lr * 4];
            uint4 u1 = *(const uint4*)&xs1u[(size_t)sj1 * 64 + lr * 4];
            uint4 u2 = *(const uint4*)&xs1u[(size_t)sj2 * 64 + lr * 4];
            uint4 u3 = *(const uint4*)&xs1u[(size_t)sj3 * 64 + lr * 4];
            f32x2_t W0 = {ww0, ww0}, W1v = {ww1, ww1}, W2v = {ww2, ww2}, W3v = {ww3, ww3};
            acc2[0] += W0 * bfpair(u0.x); acc2[1] += W0 * bfpair(u0.y);
            acc2[2] += W0 * bfpair(u0.z); acc2[3] += W0 * bfpair(u0.w);
            acc2[0] += W1v * bfpair(u1.x); acc2[1] += W1v * bfpair(u1.y);
            acc2[2] += W1v * bfpair(u1.z); acc2[3] += W1v * bfpair(u1.w);
            acc2[0] += W2v * bfpair(u2.x); acc2[1] += W2v * bfpair(u2.y);
            acc2[2] += W2v * bfpair(u2.z); acc2[3] += W2v * bfpair(u2.w);
            acc2[0] += W3v * bfpair(u3.x); acc2[1] += W3v * bfpair(u3.y);
            acc2[2] += W3v * bfpair(u3.z); acc2[3] += W3v * bfpair(u3.w);
        }
        __builtin_amdgcn_wave_barrier();
    }
#pragma unroll
    for (int d = 8; d >= 1; d >>= 1) {
        ds0 += __shfl_xor(ds0, d, 16); ds1 += __shfl_xor(ds1, d, 16);
        ds2 += __shfl_xor(ds2, d, 16); ds3 += __shfl_xor(ds3, d, 16);
        s0 += __shfl_xor(s0, d, 16);   s1 += __shfl_xor(s1, d, 16);
        s2 += __shfl_xor(s2, d, 16);   s3 += __shfl_xor(s3, d, 16);
    }
    float invd = 1.f / fmaxf((float)deg, 1.f);
    float aL0 = asn.x + adn.x + s0 * invd;
    float aL1 = asn.y + adn.y + s1 * invd;
    float aL2 = asn.z + adn.z + s2 * invd;
    float aL3 = asn.w + adn.w + s3 * invd;
    aL0 = aL0 >= 0.f ? aL0 : 0.2f * aL0;
    aL1 = aL1 >= 0.f ? aL1 : 0.2f * aL1;
    aL2 = aL2 >= 0.f ? aL2 : 0.2f * aL2;
    aL3 = aL3 >= 0.f ? aL3 : 0.2f * aL3;
    float ws0 = __expf(aL0), ws1 = __expf(aL1), ws2 = __expf(aL2), ws3 = __expf(aL3);
    float wself = qh == 0 ? ws0 : (qh == 1 ? ws1 : (qh == 2 ? ws2 : ws3));
    float dh = qh == 0 ? ds0 + ws0 : (qh == 1 ? ds1 + ws1 : (qh == 2 ? ds2 + ws2 : ds3 + ws3));
    uint4 us = *(const uint4*)&xs1u[(size_t)n * 64 + lr * 4];
    f32x2_t Ws = {wself, wself};
    acc2[0] += Ws * bfpair(us.x); acc2[1] += Ws * bfpair(us.y);
    acc2[2] += Ws * bfpair(us.z); acc2[3] += Ws * bfpair(us.w);
    float inv = 1.f / (dh + 1e-16f);
    int c = lr * 8;
    uint4 ou;
    unsigned* op = (unsigned*)&ou;
#pragma unroll
    for (int k2 = 0; k2 < 4; ++k2) {
        int c0 = c + 2 * k2, c1 = c + 2 * k2 + 1;
        float o0 = acc2[k2][0] * inv + b1[c0];
        float o1 = acc2[k2][1] * inv + b1[c1];
        float sc0 = g1[c0] * rsqrtf(rv1[c0] + 1e-5f);
        float sc1 = g1[c1] * rsqrtf(rv1[c1] + 1e-5f);
        o0 = (o0 - rm1[c0]) * sc0 + be1[c0];
        o1 = (o1 - rm1[c1]) * sc1 + be1[c1];
        o0 = o0 > 0.f ? o0 : __expf(o0) - 1.f;
        o1 = o1 > 0.f ? o1 : __expf(o1) - 1.f;
        op[k2] = f2bf2(o0, o1);
    }
    *(uint4*)&h1u[(size_t)n * 64 + lr * 4] = ou;
}

// ---------------------------------------------------------------------------
// K6: MFMA GEMM2 + fused alpha2 epilogue. xs2 tile staged in LDS; 4 threads
// per row compute the two 40-dim attention dots (width-4 shfl reduce).
__global__ __launch_bounds__(256) void gemm2_alpha2(
    const unsigned* __restrict__ A, const unsigned* __restrict__ w2t,
    unsigned* __restrict__ out, const float* __restrict__ asw,
    const float* __restrict__ adw, float* __restrict__ as2, float* __restrict__ ad2) {
    __shared__ unsigned sA[64 * 68];
    __shared__ unsigned sB[48 * 68];
    __shared__ unsigned hX[64 * 24];
    int t = threadIdx.x;
    int row0 = blockIdx.x * 64;
    for (int i = t; i < 64 * 16; i += 256) {
        int r = i >> 4, q = i & 15;
        int gr = row0 + r;
        uint4 v = (gr < NN) ? *(const uint4*)&A[(size_t)gr * 64 + q * 4]
                            : make_uint4(0u, 0u, 0u, 0u);
        *(uint4*)&sA[r * 68 + q * 4] = v;
    }
    for (int i = t; i < 48 * 16; i += 256) {
        int c = i >> 4, q = i & 15;
        *(uint4*)&sB[c * 68 + q * 4] = *(const uint4*)&w2t[c * 64 + q * 4];
    }
    __syncthreads();
    int wv = t >> 6, lane = t & 63;
    int lr = lane & 15, kgrp = lane >> 4;
    f32x4_t acc[3];
#pragma unroll
    for (int i = 0; i < 3; ++i) acc[i] = (f32x4_t){0.f, 0.f, 0.f, 0.f};
    int arow = wv * 16 + lr;
#pragma unroll
    for (int kt = 0; kt < 4; ++kt) {
        int kw = kt * 16 + kgrp * 4;
        s16x8_t af = *(const s16x8_t*)&sA[arow * 68 + kw];
#pragma unroll
        for (int tc = 0; tc < 3; ++tc) {
            s16x8_t bf = *(const s16x8_t*)&sB[(tc * 16 + lr) * 68 + kw];
            acc[tc] = __builtin_amdgcn_mfma_f32_16x16x32_bf16(af, bf, acc[tc], 0, 0, 0);
        }
    }
    int orow0l = wv * 16 + kgrp * 4;     // row within tile
#pragma unroll
    for (int tc = 0; tc < 3; ++tc) {
#pragma unroll
        for (int r = 0; r < 4; ++r) {
            float v = acc[tc][r];
            float other = __shfl_xor(v, 1);
            int lrow = orow0l + r;
            int gr = row0 + lrow;
            if (!(lane & 1) && (tc < 2 || lr < 8)) {
                unsigned u = f2bf2(v, other);
                hX[lrow * 24 + tc * 8 + (lr >> 1)] = u;
                if (gr < NN) out[(size_t)gr * 32 + tc * 8 + (lr >> 1)] = u;
            }
        }
    }
    __syncthreads();
    // alpha2: 4 threads per row, 5 uints each, width-4 reduce.
    {
        int r = t >> 2, q = t & 3;
        int gr = row0 + r;
        float pa = 0.f, pd = 0.f;
#pragma unroll
        for (int k = 0; k < 5; ++k) {
            int cidx = q * 5 + k;
            unsigned u = hX[r * 24 + cidx];
            int c = cidx * 2;
            pa += bf_lo(u) * asw[c] + bf_hi(u) * asw[c + 1];
            pd += bf_lo(u) * adw[c] + bf_hi(u) * adw[c + 1];
        }
        pa += __shfl_xor(pa, 1, 4); pa += __shfl_xor(pa, 2, 4);
        pd += __shfl_xor(pd, 1, 4); pd += __shfl_xor(pd, 2, 4);
        if (q == 0 && gr < NN) { as2[gr] = pa; ad2[gr] = pd; }
    }
}

// ---------------------------------------------------------------------------
// K7: layer-2 GAT aggregation + bias + BN + log_softmax.
__global__ __launch_bounds__(256) void gat2_kernel(
    const uint4* __restrict__ epk, const int* __restrict__ off,
    const unsigned* __restrict__ xs2u,
    const float* __restrict__ as2, const float* __restrict__ ad2,
    const float* __restrict__ b2, const float* __restrict__ g2, const float* __restrict__ be2,
    const float* __restrict__ rm2, const float* __restrict__ rv2, float* __restrict__ outp) {
    __shared__ int   lds_s[4][72];
    __shared__ float lds_w[4][72];
    int wid = (blockIdx.x * 256 + threadIdx.x) >> 6;
    if (wid >= NN) return;
    int lane = threadIdx.x & 63;
    int warp = threadIdx.x >> 6;
    int n = wid;
    int e0 = off[n], e1 = off[n + 1];
    int deg = e1 - e0;
    int grp3 = lane / 20;
    int col = lane - grp3 * 20;
    bool act = grp3 < 3;
    int grpo = act ? grp3 : 0;
    if (lane < 8) {
        lds_s[warp][64 + lane] = 0;
        lds_w[warp][64 + lane] = 0.f;
    }
    float adn = ad2[n];
    float asn = as2[n];
    f32x2_t acc2 = {0.f, 0.f};
    float dsum = 0.f, aesum = 0.f;

    for (int base = 0; base < deg; base += 64) {
        int i = base + lane;
        int cn = min(64, deg - base);
        int s = 0;
        float w = 0.f;
        if (i < deg) {
            uint4 ep = epk[e0 + i];
            s = (int)ep.x;
            float ae = __uint_as_float(ep.w);
            float a = as2[s] + adn + ae;
            a = a >= 0.f ? a : 0.2f * a;
            w = __expf(a);
            dsum += w;
            aesum += ae;
        }
        lds_s[warp][lane] = s;
        lds_w[warp][lane] = w;
        __builtin_amdgcn_wave_barrier();
        int cnr = ((cn + 11) / 12) * 12;            // <= 72; jj max = 71
        for (int j = 0; j < cnr; j += 12) {
            int jj0 = j + grpo, jj1 = jj0 + 3, jj2 = jj0 + 6, jj3 = jj0 + 9;
            int sj0 = lds_s[warp][jj0];
            int sj1 = lds_s[warp][jj1];
            int sj2 = lds_s[warp][jj2];
            int sj3 = lds_s[warp][jj3];
            float w0 = act ? lds_w[warp][jj0] : 0.f;
            float w1 = act ? lds_w[warp][jj1] : 0.f;
            float w2 = act ? lds_w[warp][jj2] : 0.f;
            float w3 = act ? lds_w[warp][jj3] : 0.f;
            unsigned u0 = xs2u[(size_t)sj0 * 32 + col];
            unsigned u1 = xs2u[(size_t)sj1 * 32 + col];
            unsigned u2 = xs2u[(size_t)sj2 * 32 + col];
            unsigned u3 = xs2u[(size_t)sj3 * 32 + col];
            acc2 += (f32x2_t){w0, w0} * bfpair(u0);
            acc2 += (f32x2_t){w1, w1} * bfpair(u1);
            acc2 += (f32x2_t){w2, w2} * bfpair(u2);
            acc2 += (f32x2_t){w3, w3} * bfpair(u3);
        }
        __builtin_amdgcn_wave_barrier();
    }
    {
        float p0 = __shfl(acc2[0], (lane + 20) & 63);
        float p1 = __shfl(acc2[1], (lane + 20) & 63);
        float q0 = __shfl(acc2[0], (lane + 40) & 63);
        float q1 = __shfl(acc2[1], (lane + 40) & 63);
        acc2[0] += p0 + q0;
        acc2[1] += p1 + q1;
    }
#pragma unroll
    for (int d = 32; d >= 1; d >>= 1) {
        dsum += __shfl_xor(dsum, d);
        aesum += __shfl_xor(aesum, d);
    }
    float invd = 1.f / fmaxf((float)deg, 1.f);
    float aL = asn + adn + aesum * invd;
    aL = aL >= 0.f ? aL : 0.2f * aL;
    float wself = __expf(aL);
    float denom = dsum + wself;

    float v0 = 0.f, v1 = 0.f;
    if (lane < 20) {
        unsigned u = xs2u[(size_t)n * 32 + lane];
        acc2[0] += wself * bf_lo(u);
        acc2[1] += wself * bf_hi(u);
        int c = lane * 2;
        float inv = 1.f / (denom + 1e-16f);
        v0 = acc2[0] * inv + b2[c];
        v1 = acc2[1] * inv + b2[c + 1];
        float sc0 = g2[c] * rsqrtf(rv2[c] + 1e-5f);
        float sc1 = g2[c + 1] * rsqrtf(rv2[c + 1] + 1e-5f);
        v0 = (v0 - rm2[c]) * sc0 + be2[c];
        v1 = (v1 - rm2[c + 1]) * sc1 + be2[c + 1];
    }
    float mx = (lane < 20) ? fmaxf(v0, v1) : -3.0e38f;
#pragma unroll
    for (int d = 32; d >= 1; d >>= 1) mx = fmaxf(mx, __shfl_xor(mx, d));
    float ex = (lane < 20) ? __expf(v0 - mx) + __expf(v1 - mx) : 0.f;
#pragma unroll
    for (int d = 32; d >= 1; d >>= 1) ex += __shfl_xor(ex, d);
    if (lane < 20) {
        float ls = __logf(ex);
        *(float2*)&outp[(size_t)n * 40 + lane * 2] = make_float2(v0 - mx - ls, v1 - mx - ls);
    }
}

// ---------------------------------------------------------------------------
extern "C" void kernel_launch(void* const* d_in, const int* in_sizes, int n_in,
                              void* d_out, int out_size, void* d_ws, size_t ws_size,
                              hipStream_t stream) {
    const float* x     = (const float*)d_in[0];
    const int*   ei    = (const int*)d_in[1];
    const float* eattr = (const float*)d_in[2];
    const float* W1    = (const float*)d_in[3];
    const float* as1w  = (const float*)d_in[4];
    const float* ad1w  = (const float*)d_in[5];
    const float* ae1w  = (const float*)d_in[6];
    const float* We1   = (const float*)d_in[7];
    const float* b1    = (const float*)d_in[8];
    const float* W2    = (const float*)d_in[9];
    const float* as2w  = (const float*)d_in[10];
    const float* ad2w  = (const float*)d_in[11];
    const float* ae2w  = (const float*)d_in[12];
    const float* We2   = (const float*)d_in[13];
    const float* b2    = (const float*)d_in[14];
    const float* g1    = (const float*)d_in[15];
    const float* be1   = (const float*)d_in[16];
    const float* rm1   = (const float*)d_in[17];
    const float* rv1   = (const float*)d_in[18];
    const float* g2    = (const float*)d_in[19];
    const float* be2   = (const float*)d_in[20];
    const float* rm2   = (const float*)d_in[21];
    const float* rv2   = (const float*)d_in[22];

    const int* src0 = ei;
    const int* dst0 = ei + NE;

    char* p = (char*)d_ws;
    auto take = [&](size_t nbytes) {
        void* r = (void*)p;
        p += (nbytes + 255) & ~(size_t)255;
        return r;
    };
    float*    wf1    = (float*)take(80);
    float*    wf2    = (float*)take(20);
    unsigned* w1t    = (unsigned*)take((size_t)128 * 64 * 4);
    unsigned* w2t    = (unsigned*)take((size_t)48 * 64 * 4);
    int*      cnt    = (int*)take((size_t)NN * 4);
    int*      off    = (int*)take((size_t)(NN + 1) * 4);
    int*      bsum   = (int*)take((size_t)SCAN_NB * 4);
    int*      rank   = (int*)take((size_t)NE * 4);
    uint4*    epk    = (uint4*)take((size_t)NE * 16);
    float*    as1    = (float*)take((size_t)NN * 16);
    float*    ad1    = (float*)take((size_t)NN * 16);
    float*    as2    = (float*)take((size_t)NN * 4);
    float*    ad2    = (float*)take((size_t)NN * 4);
    unsigned* xs1u   = (unsigned*)take((size_t)NN * 256);  // 64 uints/row
    unsigned* h1u    = (unsigned*)take((size_t)NN * 256);
    unsigned* xs2u   = (unsigned*)take((size_t)NN * 128);  // 32 uints/row

    prep_kernel<<<SCAN_NB, 256, 0, stream>>>(We1, ae1w, We2, ae2w, W1, W2, wf1, wf2,
                                             w1t, w2t, cnt);
    count_gemm1<<<CNT_NB + G1_NB, 256, 0, stream>>>(dst0, cnt, rank, x, w1t, xs1u);
    scan1_alpha1<<<SCAN_NB + A1_NB, 256, 0, stream>>>(cnt, off, bsum, xs1u, as1w, ad1w,
                                                      as1, ad1);
    scan3_kernel<<<SCAN_NB, 256, 0, stream>>>(off, bsum, cnt);
    fill_fold_kernel<<<(NE + 1023) / 1024, 256, 0, stream>>>(src0, dst0, eattr, wf1, wf2,
                                                             off, rank, epk);
    gat1_kernel<<<NN / 16, 256, 0, stream>>>(epk, off, xs1u, (const float4*)as1,
                                             (const float4*)ad1, b1, g1, be1, rm1, rv1, h1u);
    gemm2_alpha2<<<(NN + 63) / 64, 256, 0, stream>>>(h1u, w2t, xs2u, as2w, ad2w, as2, ad2);
    gat2_kernel<<<(NN + 3) / 4, 256, 0, stream>>>(epk, off, xs2u, as2, ad2,
                                                  b2, g2, be2, rm2, rv2, (float*)d_out);
}

// Round 18
// 164.685 us; speedup vs baseline: 1.0917x; 1.0083x over previous
//
#include <hip/hip_runtime.h>
#include <hip/hip_bf16.h>

#define NN 50000
#define NE 800000
#define SCAN_NB ((NN + 255) / 256)   // 196 blocks
#define CNT_NB ((NE + 255) / 256)    // 3125 blocks
#define G1_NB ((NN + 63) / 64)       // 782 blocks
#define A1_NB ((NN + 3) / 4)         // 12500 blocks
#define FF_NB ((NE + 1023) / 1024)   // 782 blocks
// IN=128, HID=32, HEADS=4, HC=128, OUT=40, EDIM=5

typedef float f32x4_t __attribute__((ext_vector_type(4)));
typedef float f32x2_t __attribute__((ext_vector_type(2)));
typedef short s16x8_t __attribute__((ext_vector_type(8)));

// bf16 pack/unpack helpers (RNE rounding).
__device__ __forceinline__ unsigned f2bf2(float a, float b) {
    unsigned ua = __float_as_uint(a);
    ua = (ua + 0x7fffu + ((ua >> 16) & 1u)) >> 16;
    unsigned ub = __float_as_uint(b);
    ub = (ub + 0x7fffu + ((ub >> 16) & 1u)) >> 16;
    return ua | (ub << 16);
}
__device__ __forceinline__ float bf_lo(unsigned u) { return __uint_as_float(u << 16); }
__device__ __forceinline__ float bf_hi(unsigned u) { return __uint_as_float(u & 0xffff0000u); }
__device__ __forceinline__ f32x2_t bfpair(unsigned u) {
    return (f32x2_t){__uint_as_float(u << 16), __uint_as_float(u & 0xffff0000u)};
}

// ---------------------------------------------------------------------------
// K0: prep — zero cnt (grid-wide) + folds + bf16-transposed GEMM weights.
__global__ __launch_bounds__(256) void prep_kernel(
    const float* __restrict__ We1, const float* __restrict__ ae1w,
    const float* __restrict__ We2, const float* __restrict__ ae2w,
    const float* __restrict__ W1, const float* __restrict__ W2,
    float* __restrict__ wf1, float* __restrict__ wf2,
    unsigned* __restrict__ w1t, unsigned* __restrict__ w2t,
    int* __restrict__ cnt) {
    int t = threadIdx.x;
    int g = blockIdx.x * 256 + t;
    if (g < NN) cnt[g] = 0;
    if (blockIdx.x != 0) return;
    if (t < 20) {
        int j = t >> 2, h = t & 3;
        float s = 0.f;
        for (int c = 0; c < 32; ++c) s += We1[j * 128 + h * 32 + c] * ae1w[h * 32 + c];
        wf1[j * 4 + h] = s;
    }
    if (t >= 32 && t < 37) {
        int j = t - 32;
        float s = 0.f;
        for (int c = 0; c < 40; ++c) s += We2[j * 40 + c] * ae2w[c];
        wf2[j] = s;
    }
    for (int i = t; i < 128 * 64; i += 256) {
        int c = i >> 6, kp = i & 63;
        w1t[i] = f2bf2(W1[(size_t)(2 * kp) * 128 + c], W1[(size_t)(2 * kp + 1) * 128 + c]);
    }
    for (int i = t; i < 48 * 64; i += 256) {
        int c = i >> 6, kp = i & 63;
        w2t[i] = (c < 40) ? f2bf2(W2[(size_t)(2 * kp) * 40 + c], W2[(size_t)(2 * kp + 1) * 40 + c]) : 0u;
    }
}

// ---------------------------------------------------------------------------
// K1: MERGED [count+rank || MFMA GEMM1] (measured best structure).
__global__ __launch_bounds__(256) void count_gemm1(
    const int* __restrict__ dst0, int* __restrict__ cnt, int* __restrict__ rank,
    const float* __restrict__ A, const unsigned* __restrict__ w1t,
    unsigned* __restrict__ out) {
    if (blockIdx.x < CNT_NB) {
        int e = blockIdx.x * 256 + threadIdx.x;
        if (e < NE) rank[e] = atomicAdd(&cnt[dst0[e]], 1);
        return;
    }
    __shared__ unsigned sA[64 * 68];
    __shared__ unsigned sB[128 * 68];
    int t = threadIdx.x;
    int row0 = (blockIdx.x - CNT_NB) * 64;
    for (int i = t; i < 64 * 32; i += 256) {
        int r = i >> 5, q = i & 31;
        int gr = row0 + r;
        float4 v = (gr < NN) ? *(const float4*)&A[(size_t)gr * 128 + q * 4]
                             : make_float4(0.f, 0.f, 0.f, 0.f);
        sA[r * 68 + q * 2]     = f2bf2(v.x, v.y);
        sA[r * 68 + q * 2 + 1] = f2bf2(v.z, v.w);
    }
    for (int i = t; i < 128 * 16; i += 256) {
        int c = i >> 4, q = i & 15;
        *(uint4*)&sB[c * 68 + q * 4] = *(const uint4*)&w1t[c * 64 + q * 4];
    }
    __syncthreads();
    int wv = t >> 6, lane = t & 63;
    int lr = lane & 15, kgrp = lane >> 4;
    f32x4_t acc[8];
#pragma unroll
    for (int i = 0; i < 8; ++i) acc[i] = (f32x4_t){0.f, 0.f, 0.f, 0.f};
    int arow = wv * 16 + lr;
#pragma unroll
    for (int kt = 0; kt < 4; ++kt) {
        int kw = kt * 16 + kgrp * 4;
        s16x8_t af = *(const s16x8_t*)&sA[arow * 68 + kw];
#pragma unroll
        for (int tc = 0; tc < 8; ++tc) {
            s16x8_t bf = *(const s16x8_t*)&sB[(tc * 16 + lr) * 68 + kw];
            acc[tc] = __builtin_amdgcn_mfma_f32_16x16x32_bf16(af, bf, acc[tc], 0, 0, 0);
        }
    }
    int orow0 = row0 + wv * 16 + kgrp * 4;
#pragma unroll
    for (int tc = 0; tc < 8; ++tc) {
#pragma unroll
        for (int r = 0; r < 4; ++r) {
            float v = acc[tc][r];
            float other = __shfl_xor(v, 1);
            int gr = orow0 + r;
            if (!(lane & 1) && gr < NN)
                out[(size_t)gr * 64 + tc * 8 + (lr >> 1)] = f2bf2(v, other);
        }
    }
}

// ---------------------------------------------------------------------------
// K2: MERGED [scan1 || alpha1]. off gets PARTIAL (within-block) prefixes;
// bsum gets RAW per-block sums.
__global__ __launch_bounds__(256) void scan1_alpha1(
    const int* __restrict__ cnt, int* __restrict__ off, int* __restrict__ bsum,
    const unsigned* __restrict__ xs1u, const float* __restrict__ asw,
    const float* __restrict__ adw, float* __restrict__ as1, float* __restrict__ ad1) {
    if (blockIdx.x < SCAN_NB) {
        __shared__ int tmp[256];
        int t = threadIdx.x;
        int g = blockIdx.x * 256 + t;
        int v = (g < NN) ? cnt[g] : 0;
        tmp[t] = v;
        __syncthreads();
#pragma unroll
        for (int d = 1; d < 256; d <<= 1) {
            int u = (t >= d) ? tmp[t - d] : 0;
            __syncthreads();
            tmp[t] += u;
            __syncthreads();
        }
        if (g < NN) off[g] = tmp[t] - v;
        if (t == 255) bsum[blockIdx.x] = tmp[255];
        return;
    }
    int wid = ((blockIdx.x - SCAN_NB) * 256 + threadIdx.x) >> 6;
    if (wid >= NN) return;
    int lane = threadIdx.x & 63;
    int c = lane * 2;
    unsigned u = xs1u[(size_t)wid * 64 + lane];
    float vx = bf_lo(u), vy = bf_hi(u);
    float pa = vx * asw[c] + vy * asw[c + 1];
    float pd = vx * adw[c] + vy * adw[c + 1];
#pragma unroll
    for (int d = 8; d >= 1; d >>= 1) {
        pa += __shfl_xor(pa, d, 16);
        pd += __shfl_xor(pd, d, 16);
    }
    if ((lane & 15) == 0) {
        as1[wid * 4 + (lane >> 4)] = pa;
        ad1[wid * 4 + (lane >> 4)] = pd;
    }
}

// ---------------------------------------------------------------------------
// K3: MERGED [scan-finalize || fill]. Blocks [0,SCAN_NB): write FINAL offsets
// to offF (separate array — no race with concurrent fill blocks reading the
// partial off). Blocks [SCAN_NB,...): fill, computing the 196-entry block
// prefix in own LDS (pos = off_partial[d] + pre[d>>8] + rank).
__global__ __launch_bounds__(256) void scanf_fill(
    const int* __restrict__ off, const int* __restrict__ bsum,
    const int* __restrict__ cnt, int* __restrict__ offF,
    const int* __restrict__ src0, const int* __restrict__ dst0,
    const float* __restrict__ eattr, const float* __restrict__ wf1,
    const float* __restrict__ wf2, const int* __restrict__ rank,
    uint4* __restrict__ epk) {
    __shared__ int tmp[256];
    int t = threadIdx.x;
    int v = (t < SCAN_NB) ? bsum[t] : 0;
    tmp[t] = v;
    __syncthreads();
#pragma unroll
    for (int d = 1; d < 256; d <<= 1) {
        int u = (t >= d) ? tmp[t - d] : 0;
        __syncthreads();
        tmp[t] += u;
        __syncthreads();
    }
    if (blockIdx.x < SCAN_NB) {
        int pre = (blockIdx.x == 0) ? 0 : tmp[blockIdx.x - 1];
        int g = blockIdx.x * 256 + t;
        if (g < NN) {
            int o = off[g] + pre;
            offF[g] = o;
            if (g == NN - 1) offF[NN] = o + cnt[g];
        }
        return;
    }
    int base = (blockIdx.x - SCAN_NB) * 1024 + t;
#pragma unroll
    for (int k = 0; k < 4; ++k) {
        int e = base + k * 256;
        if (e >= NE) continue;
        float a[5];
#pragma unroll
        for (int j = 0; j < 5; ++j) a[j] = eattr[(size_t)e * 5 + j];
        float o[4];
#pragma unroll
        for (int h = 0; h < 4; ++h) {
            float s = 0.f;
#pragma unroll
            for (int j = 0; j < 5; ++j) s += a[j] * wf1[j * 4 + h];
            o[h] = s;
        }
        float s2 = 0.f;
#pragma unroll
        for (int j = 0; j < 5; ++j) s2 += a[j] * wf2[j];
        int d = dst0[e];
        int blk = d >> 8;
        int pre = (blk == 0) ? 0 : tmp[blk - 1];
        int pos = off[d] + pre + rank[e];
        epk[pos] = make_uint4((unsigned)src0[e], f2bf2(o[0], o[1]), f2bf2(o[2], o[3]),
                              __float_as_uint(s2));
    }
}

// ---------------------------------------------------------------------------
// K4: layer-1 GAT aggregation. 4 nodes/wave, 16 lanes/node.
__global__ __launch_bounds__(256) void gat1_kernel(
    const uint4* __restrict__ epk, const int* __restrict__ off,
    const unsigned* __restrict__ xs1u,
    const float4* __restrict__ as1, const float4* __restrict__ ad1,
    const float* __restrict__ b1, const float* __restrict__ g1, const float* __restrict__ be1,
    const float* __restrict__ rm1, const float* __restrict__ rv1, unsigned* __restrict__ h1u) {
    __shared__ int   lds_s[4][4][16];
    __shared__ float lds_w[4][4][16][4];
    int wave = threadIdx.x >> 6;
    int lane = threadIdx.x & 63;
    int g = lane >> 4;
    int lr = lane & 15;
    int qh = lr >> 2;
    int n = blockIdx.x * 16 + wave * 4 + g;
    int e0 = off[n];
    int deg = off[n + 1] - e0;
    float4 adn = ad1[n];
    float4 asn = as1[n];
    f32x2_t acc2[4];
#pragma unroll
    for (int k = 0; k < 4; ++k) acc2[k] = (f32x2_t){0.f, 0.f};
    float ds0 = 0.f, ds1 = 0.f, ds2 = 0.f, ds3 = 0.f;
    float s0 = 0.f, s1 = 0.f, s2 = 0.f, s3 = 0.f;
    int mc = (deg + 15) >> 4;
    mc = max(mc, __shfl_xor(mc, 16));
    mc = max(mc, __shfl_xor(mc, 32));

    for (int ch = 0; ch < mc; ++ch) {
        int i = ch * 16 + lr;
        int s = 0;
        float w0 = 0.f, w1 = 0.f, w2 = 0.f, w3 = 0.f;
        if (i < deg) {
            uint4 ep = epk[e0 + i];
            s = (int)ep.x;
            float ax = bf_lo(ep.y), ay = bf_hi(ep.y);
            float az = bf_lo(ep.z), aw = bf_hi(ep.z);
            float4 av = as1[s];
            float a0 = av.x + adn.x + ax;
            float a1 = av.y + adn.y + ay;
            float a2 = av.z + adn.z + az;
            float a3 = av.w + adn.w + aw;
            a0 = a0 >= 0.f ? a0 : 0.2f * a0;
            a1 = a1 >= 0.f ? a1 : 0.2f * a1;
            a2 = a2 >= 0.f ? a2 : 0.2f * a2;
            a3 = a3 >= 0.f ? a3 : 0.2f * a3;
            w0 = __expf(a0); w1 = __expf(a1); w2 = __expf(a2); w3 = __expf(a3);
            ds0 += w0; ds1 += w1; ds2 += w2; ds3 += w3;
            s0 += ax; s1 += ay; s2 += az; s3 += aw;
        }
        lds_s[wave][g][lr] = s;
        *(float4*)&lds_w[wave][g][lr][0] = make_float4(w0, w1, w2, w3);
        __builtin_amdgcn_wave_barrier();
        int cn = deg - ch * 16;
        cn = cn > 16 ? 16 : (cn < 0 ? 0 : cn);
        int cnr = (cn + 3) & ~3;
        for (int j = 0; j < cnr; j += 4) {
            int sj0 = lds_s[wave][g][j];
            int sj1 = lds_s[wave][g][j + 1];
            int sj2 = lds_s[wave][g][j + 2];
            int sj3 = lds_s[wave][g][j + 3];
            float ww0 = lds_w[wave][g][j][qh];
            float ww1 = lds_w[wave][g][j + 1][qh];
            float ww2 = lds_w[wave][g][j + 2][qh];
            float ww3 = lds_w[wave][g][j + 3][qh];
            uint4 u0 = *(const uint4*)&xs1u[(size_t)sj0 * 64 + lr * 4];
            uint4 u1 = *(const uint4*)&xs1u[(size_t)sj1 * 64 + lr * 4];
            uint4 u2 = *(const uint4*)&xs1u[(size_t)sj2 * 64 + lr * 4];
            uint4 u3 = *(const uint4*)&xs1u[(size_t)sj3 * 64 + lr * 4];
            f32x2_t W0 = {ww0, ww0}, W1v = {ww1, ww1}, W2v = {ww2, ww2}, W3v = {ww3, ww3};
            acc2[0] += W0 * bfpair(u0.x); acc2[1] += W0 * bfpair(u0.y);
            acc2[2] += W0 * bfpair(u0.z); acc2[3] += W0 * bfpair(u0.w);
            acc2[0] += W1v * bfpair(u1.x); acc2[1] += W1v * bfpair(u1.y);
            acc2[2] += W1v * bfpair(u1.z); acc2[3] += W1v * bfpair(u1.w);
            acc2[0] += W2v * bfpair(u2.x); acc2[1] += W2v * bfpair(u2.y);
            acc2[2] += W2v * bfpair(u2.z); acc2[3] += W2v * bfpair(u2.w);
            acc2[0] += W3v * bfpair(u3.x); acc2[1] += W3v * bfpair(u3.y);
            acc2[2] += W3v * bfpair(u3.z); acc2[3] += W3v * bfpair(u3.w);
        }
        __builtin_amdgcn_wave_barrier();
    }
#pragma unroll
    for (int d = 8; d >= 1; d >>= 1) {
        ds0 += __shfl_xor(ds0, d, 16); ds1 += __shfl_xor(ds1, d, 16);
        ds2 += __shfl_xor(ds2, d, 16); ds3 += __shfl_xor(ds3, d, 16);
        s0 += __shfl_xor(s0, d, 16);   s1 += __shfl_xor(s1, d, 16);
        s2 += __shfl_xor(s2, d, 16);   s3 += __shfl_xor(s3, d, 16);
    }
    float invd = 1.f / fmaxf((float)deg, 1.f);
    float aL0 = asn.x + adn.x + s0 * invd;
    float aL1 = asn.y + adn.y + s1 * invd;
    float aL2 = asn.z + adn.z + s2 * invd;
    float aL3 = asn.w + adn.w + s3 * invd;
    aL0 = aL0 >= 0.f ? aL0 : 0.2f * aL0;
    aL1 = aL1 >= 0.f ? aL1 : 0.2f * aL1;
    aL2 = aL2 >= 0.f ? aL2 : 0.2f * aL2;
    aL3 = aL3 >= 0.f ? aL3 : 0.2f * aL3;
    float ws0 = __expf(aL0), ws1 = __expf(aL1), ws2 = __expf(aL2), ws3 = __expf(aL3);
    float wself = qh == 0 ? ws0 : (qh == 1 ? ws1 : (qh == 2 ? ws2 : ws3));
    float dh = qh == 0 ? ds0 + ws0 : (qh == 1 ? ds1 + ws1 : (qh == 2 ? ds2 + ws2 : ds3 + ws3));
    uint4 us = *(const uint4*)&xs1u[(size_t)n * 64 + lr * 4];
    f32x2_t Ws = {wself, wself};
    acc2[0] += Ws * bfpair(us.x); acc2[1] += Ws * bfpair(us.y);
    acc2[2] += Ws * bfpair(us.z); acc2[3] += Ws * bfpair(us.w);
    float inv = 1.f / (dh + 1e-16f);
    int c = lr * 8;
    uint4 ou;
    unsigned* op = (unsigned*)&ou;
#pragma unroll
    for (int k2 = 0; k2 < 4; ++k2) {
        int c0 = c + 2 * k2, c1 = c + 2 * k2 + 1;
        float o0 = acc2[k2][0] * inv + b1[c0];
        float o1 = acc2[k2][1] * inv + b1[c1];
        float sc0 = g1[c0] * rsqrtf(rv1[c0] + 1e-5f);
        float sc1 = g1[c1] * rsqrtf(rv1[c1] + 1e-5f);
        o0 = (o0 - rm1[c0]) * sc0 + be1[c0];
        o1 = (o1 - rm1[c1]) * sc1 + be1[c1];
        o0 = o0 > 0.f ? o0 : __expf(o0) - 1.f;
        o1 = o1 > 0.f ? o1 : __expf(o1) - 1.f;
        op[k2] = f2bf2(o0, o1);
    }
    *(uint4*)&h1u[(size_t)n * 64 + lr * 4] = ou;
}

// ---------------------------------------------------------------------------
// K5: MFMA GEMM2 + fused alpha2 epilogue.
__global__ __launch_bounds__(256) void gemm2_alpha2(
    const unsigned* __restrict__ A, const unsigned* __restrict__ w2t,
    unsigned* __restrict__ out, const float* __restrict__ asw,
    const float* __restrict__ adw, float* __restrict__ as2, float* __restrict__ ad2) {
    __shared__ unsigned sA[64 * 68];
    __shared__ unsigned sB[48 * 68];
    __shared__ unsigned hX[64 * 24];
    int t = threadIdx.x;
    int row0 = blockIdx.x * 64;
    for (int i = t; i < 64 * 16; i += 256) {
        int r = i >> 4, q = i & 15;
        int gr = row0 + r;
        uint4 v = (gr < NN) ? *(const uint4*)&A[(size_t)gr * 64 + q * 4]
                            : make_uint4(0u, 0u, 0u, 0u);
        *(uint4*)&sA[r * 68 + q * 4] = v;
    }
    for (int i = t; i < 48 * 16; i += 256) {
        int c = i >> 4, q = i & 15;
        *(uint4*)&sB[c * 68 + q * 4] = *(const uint4*)&w2t[c * 64 + q * 4];
    }
    __syncthreads();
    int wv = t >> 6, lane = t & 63;
    int lr = lane & 15, kgrp = lane >> 4;
    f32x4_t acc[3];
#pragma unroll
    for (int i = 0; i < 3; ++i) acc[i] = (f32x4_t){0.f, 0.f, 0.f, 0.f};
    int arow = wv * 16 + lr;
#pragma unroll
    for (int kt = 0; kt < 4; ++kt) {
        int kw = kt * 16 + kgrp * 4;
        s16x8_t af = *(const s16x8_t*)&sA[arow * 68 + kw];
#pragma unroll
        for (int tc = 0; tc < 3; ++tc) {
            s16x8_t bf = *(const s16x8_t*)&sB[(tc * 16 + lr) * 68 + kw];
            acc[tc] = __builtin_amdgcn_mfma_f32_16x16x32_bf16(af, bf, acc[tc], 0, 0, 0);
        }
    }
    int orow0l = wv * 16 + kgrp * 4;
#pragma unroll
    for (int tc = 0; tc < 3; ++tc) {
#pragma unroll
        for (int r = 0; r < 4; ++r) {
            float v = acc[tc][r];
            float other = __shfl_xor(v, 1);
            int lrow = orow0l + r;
            int gr = row0 + lrow;
            if (!(lane & 1) && (tc < 2 || lr < 8)) {
                unsigned u = f2bf2(v, other);
                hX[lrow * 24 + tc * 8 + (lr >> 1)] = u;
                if (gr < NN) out[(size_t)gr * 32 + tc * 8 + (lr >> 1)] = u;
            }
        }
    }
    __syncthreads();
    {
        int r = t >> 2, q = t & 3;
        int gr = row0 + r;
        float pa = 0.f, pd = 0.f;
#pragma unroll
        for (int k = 0; k < 5; ++k) {
            int cidx = q * 5 + k;
            unsigned u = hX[r * 24 + cidx];
            int c = cidx * 2;
            pa += bf_lo(u) * asw[c] + bf_hi(u) * asw[c + 1];
            pd += bf_lo(u) * adw[c] + bf_hi(u) * adw[c + 1];
        }
        pa += __shfl_xor(pa, 1, 4); pa += __shfl_xor(pa, 2, 4);
        pd += __shfl_xor(pd, 1, 4); pd += __shfl_xor(pd, 2, 4);
        if (q == 0 && gr < NN) { as2[gr] = pa; ad2[gr] = pd; }
    }
}

// ---------------------------------------------------------------------------
// K6: layer-2 GAT aggregation + bias + BN + log_softmax.
__global__ __launch_bounds__(256) void gat2_kernel(
    const uint4* __restrict__ epk, const int* __restrict__ off,
    const unsigned* __restrict__ xs2u,
    const float* __restrict__ as2, const float* __restrict__ ad2,
    const float* __restrict__ b2, const float* __restrict__ g2, const float* __restrict__ be2,
    const float* __restrict__ rm2, const float* __restrict__ rv2, float* __restrict__ outp) {
    __shared__ int   lds_s[4][72];
    __shared__ float lds_w[4][72];
    int wid = (blockIdx.x * 256 + threadIdx.x) >> 6;
    if (wid >= NN) return;
    int lane = threadIdx.x & 63;
    int warp = threadIdx.x >> 6;
    int n = wid;
    int e0 = off[n], e1 = off[n + 1];
    int deg = e1 - e0;
    int grp3 = lane / 20;
    int col = lane - grp3 * 20;
    bool act = grp3 < 3;
    int grpo = act ? grp3 : 0;
    if (lane < 8) {
        lds_s[warp][64 + lane] = 0;
        lds_w[warp][64 + lane] = 0.f;
    }
    float adn = ad2[n];
    float asn = as2[n];
    f32x2_t acc2 = {0.f, 0.f};
    float dsum = 0.f, aesum = 0.f;

    for (int base = 0; base < deg; base += 64) {
        int i = base + lane;
        int cn = min(64, deg - base);
        int s = 0;
        float w = 0.f;
        if (i < deg) {
            uint4 ep = epk[e0 + i];
            s = (int)ep.x;
            float ae = __uint_as_float(ep.w);
            float a = as2[s] + adn + ae;
            a = a >= 0.f ? a : 0.2f * a;
            w = __expf(a);
            dsum += w;
            aesum += ae;
        }
        lds_s[warp][lane] = s;
        lds_w[warp][lane] = w;
        __builtin_amdgcn_wave_barrier();
        int cnr = ((cn + 11) / 12) * 12;            // <= 72; jj max = 71
        for (int j = 0; j < cnr; j += 12) {
            int jj0 = j + grpo, jj1 = jj0 + 3, jj2 = jj0 + 6, jj3 = jj0 + 9;
            int sj0 = lds_s[warp][jj0];
            int sj1 = lds_s[warp][jj1];
            int sj2 = lds_s[warp][jj2];
            int sj3 = lds_s[warp][jj3];
            float w0 = act ? lds_w[warp][jj0] : 0.f;
            float w1 = act ? lds_w[warp][jj1] : 0.f;
            float w2 = act ? lds_w[warp][jj2] : 0.f;
            float w3 = act ? lds_w[warp][jj3] : 0.f;
            unsigned u0 = xs2u[(size_t)sj0 * 32 + col];
            unsigned u1 = xs2u[(size_t)sj1 * 32 + col];
            unsigned u2 = xs2u[(size_t)sj2 * 32 + col];
            unsigned u3 = xs2u[(size_t)sj3 * 32 + col];
            acc2 += (f32x2_t){w0, w0} * bfpair(u0);
            acc2 += (f32x2_t){w1, w1} * bfpair(u1);
            acc2 += (f32x2_t){w2, w2} * bfpair(u2);
            acc2 += (f32x2_t){w3, w3} * bfpair(u3);
        }
        __builtin_amdgcn_wave_barrier();
    }
    {
        float p0 = __shfl(acc2[0], (lane + 20) & 63);
        float p1 = __shfl(acc2[1], (lane + 20) & 63);
        float q0 = __shfl(acc2[0], (lane + 40) & 63);
        float q1 = __shfl(acc2[1], (lane + 40) & 63);
        acc2[0] += p0 + q0;
        acc2[1] += p1 + q1;
    }
#pragma unroll
    for (int d = 32; d >= 1; d >>= 1) {
        dsum += __shfl_xor(dsum, d);
        aesum += __shfl_xor(aesum, d);
    }
    float invd = 1.f / fmaxf((float)deg, 1.f);
    float aL = asn + adn + aesum * invd;
    aL = aL >= 0.f ? aL : 0.2f * aL;
    float wself = __expf(aL);
    float denom = dsum + wself;

    float v0 = 0.f, v1 = 0.f;
    if (lane < 20) {
        unsigned u = xs2u[(size_t)n * 32 + lane];
        acc2[0] += wself * bf_lo(u);
        acc2[1] += wself * bf_hi(u);
        int c = lane * 2;
        float inv = 1.f / (denom + 1e-16f);
        v0 = acc2[0] * inv + b2[c];
        v1 = acc2[1] * inv + b2[c + 1];
        float sc0 = g2[c] * rsqrtf(rv2[c] + 1e-5f);
        float sc1 = g2[c + 1] * rsqrtf(rv2[c + 1] + 1e-5f);
        v0 = (v0 - rm2[c]) * sc0 + be2[c];
        v1 = (v1 - rm2[c + 1]) * sc1 + be2[c + 1];
    }
    float mx = (lane < 20) ? fmaxf(v0, v1) : -3.0e38f;
#pragma unroll
    for (int d = 32; d >= 1; d >>= 1) mx = fmaxf(mx, __shfl_xor(mx, d));
    float ex = (lane < 20) ? __expf(v0 - mx) + __expf(v1 - mx) : 0.f;
#pragma unroll
    for (int d = 32; d >= 1; d >>= 1) ex += __shfl_xor(ex, d);
    if (lane < 20) {
        float ls = __logf(ex);
        *(float2*)&outp[(size_t)n * 40 + lane * 2] = make_float2(v0 - mx - ls, v1 - mx - ls);
    }
}

// ---------------------------------------------------------------------------
extern "C" void kernel_launch(void* const* d_in, const int* in_sizes, int n_in,
                              void* d_out, int out_size, void* d_ws, size_t ws_size,
                              hipStream_t stream) {
    const float* x     = (const float*)d_in[0];
    const int*   ei    = (const int*)d_in[1];
    const float* eattr = (const float*)d_in[2];
    const float* W1    = (const float*)d_in[3];
    const float* as1w  = (const float*)d_in[4];
    const float* ad1w  = (const float*)d_in[5];
    const float* ae1w  = (const float*)d_in[6];
    const float* We1   = (const float*)d_in[7];
    const float* b1    = (const float*)d_in[8];
    const float* W2    = (const float*)d_in[9];
    const float* as2w  = (const float*)d_in[10];
    const float* ad2w  = (const float*)d_in[11];
    const float* ae2w  = (const float*)d_in[12];
    const float* We2   = (const float*)d_in[13];
    const float* b2    = (const float*)d_in[14];
    const float* g1    = (const float*)d_in[15];
    const float* be1   = (const float*)d_in[16];
    const float* rm1   = (const float*)d_in[17];
    const float* rv1   = (const float*)d_in[18];
    const float* g2    = (const float*)d_in[19];
    const float* be2   = (const float*)d_in[20];
    const float* rm2   = (const float*)d_in[21];
    const float* rv2   = (const float*)d_in[22];

    const int* src0 = ei;
    const int* dst0 = ei + NE;

    char* p = (char*)d_ws;
    auto take = [&](size_t nbytes) {
        void* r = (void*)p;
        p += (nbytes + 255) & ~(size_t)255;
        return r;
    };
    float*    wf1    = (float*)take(80);
    float*    wf2    = (float*)take(20);
    unsigned* w1t    = (unsigned*)take((size_t)128 * 64 * 4);
    unsigned* w2t    = (unsigned*)take((size_t)48 * 64 * 4);
    int*      cnt    = (int*)take((size_t)NN * 4);
    int*      off    = (int*)take((size_t)(NN + 1) * 4);
    int*      offF   = (int*)take((size_t)(NN + 1) * 4);
    int*      bsum   = (int*)take((size_t)SCAN_NB * 4);
    int*      rank   = (int*)take((size_t)NE * 4);
    uint4*    epk    = (uint4*)take((size_t)NE * 16);
    float*    as1    = (float*)take((size_t)NN * 16);
    float*    ad1    = (float*)take((size_t)NN * 16);
    float*    as2    = (float*)take((size_t)NN * 4);
    float*    ad2    = (float*)take((size_t)NN * 4);
    unsigned* xs1u   = (unsigned*)take((size_t)NN * 256);  // 64 uints/row
    unsigned* h1u    = (unsigned*)take((size_t)NN * 256);
    unsigned* xs2u   = (unsigned*)take((size_t)NN * 128);  // 32 uints/row

    prep_kernel<<<SCAN_NB, 256, 0, stream>>>(We1, ae1w, We2, ae2w, W1, W2, wf1, wf2,
                                             w1t, w2t, cnt);
    count_gemm1<<<CNT_NB + G1_NB, 256, 0, stream>>>(dst0, cnt, rank, x, w1t, xs1u);
    scan1_alpha1<<<SCAN_NB + A1_NB, 256, 0, stream>>>(cnt, off, bsum, xs1u, as1w, ad1w,
                                                      as1, ad1);
    scanf_fill<<<SCAN_NB + FF_NB, 256, 0, stream>>>(off, bsum, cnt, offF, src0, dst0,
                                                    eattr, wf1, wf2, rank, epk);
    gat1_kernel<<<NN / 16, 256, 0, stream>>>(epk, offF, xs1u, (const float4*)as1,
                                             (const float4*)ad1, b1, g1, be1, rm1, rv1, h1u);
    gemm2_alpha2<<<(NN + 63) / 64, 256, 0, stream>>>(h1u, w2t, xs2u, as2w, ad2w, as2, ad2);
    gat2_kernel<<<(NN + 3) / 4, 256, 0, stream>>>(epk, offF, xs2u, as2, ad2,
                                                  b2, g2, be2, rm2, rv2, (float*)d_out);
}

// Round 19
// 164.421 us; speedup vs baseline: 1.0935x; 1.0016x over previous
//
#include <hip/hip_runtime.h>
#include <hip/hip_bf16.h>

#define NN 50000
#define NE 800000
#define SCAN_NB ((NN + 255) / 256)   // 196 blocks
#define CNT_NB ((NE + 255) / 256)    // 3125 blocks
#define G1_NB ((NN + 63) / 64)       // 782 blocks
#define FF_NB ((NE + 1023) / 1024)   // 782 blocks
// IN=128, HID=32, HEADS=4, HC=128, OUT=40, EDIM=5

typedef float f32x4_t __attribute__((ext_vector_type(4)));
typedef float f32x2_t __attribute__((ext_vector_type(2)));
typedef short s16x8_t __attribute__((ext_vector_type(8)));

// bf16 pack/unpack helpers (RNE rounding).
__device__ __forceinline__ unsigned f2bf2(float a, float b) {
    unsigned ua = __float_as_uint(a);
    ua = (ua + 0x7fffu + ((ua >> 16) & 1u)) >> 16;
    unsigned ub = __float_as_uint(b);
    ub = (ub + 0x7fffu + ((ub >> 16) & 1u)) >> 16;
    return ua | (ub << 16);
}
__device__ __forceinline__ float bf_lo(unsigned u) { return __uint_as_float(u << 16); }
__device__ __forceinline__ float bf_hi(unsigned u) { return __uint_as_float(u & 0xffff0000u); }
__device__ __forceinline__ f32x2_t bfpair(unsigned u) {
    return (f32x2_t){__uint_as_float(u << 16), __uint_as_float(u & 0xffff0000u)};
}

// ---------------------------------------------------------------------------
// K0: prep — zero cnt (grid-wide) + folds + bf16-transposed GEMM weights.
__global__ __launch_bounds__(256) void prep_kernel(
    const float* __restrict__ We1, const float* __restrict__ ae1w,
    const float* __restrict__ We2, const float* __restrict__ ae2w,
    const float* __restrict__ W1, const float* __restrict__ W2,
    float* __restrict__ wf1, float* __restrict__ wf2,
    unsigned* __restrict__ w1t, unsigned* __restrict__ w2t,
    int* __restrict__ cnt) {
    int t = threadIdx.x;
    int g = blockIdx.x * 256 + t;
    if (g < NN) cnt[g] = 0;
    if (blockIdx.x != 0) return;
    if (t < 20) {
        int j = t >> 2, h = t & 3;
        float s = 0.f;
        for (int c = 0; c < 32; ++c) s += We1[j * 128 + h * 32 + c] * ae1w[h * 32 + c];
        wf1[j * 4 + h] = s;
    }
    if (t >= 32 && t < 37) {
        int j = t - 32;
        float s = 0.f;
        for (int c = 0; c < 40; ++c) s += We2[j * 40 + c] * ae2w[c];
        wf2[j] = s;
    }
    for (int i = t; i < 128 * 64; i += 256) {
        int c = i >> 6, kp = i & 63;
        w1t[i] = f2bf2(W1[(size_t)(2 * kp) * 128 + c], W1[(size_t)(2 * kp + 1) * 128 + c]);
    }
    for (int i = t; i < 48 * 64; i += 256) {
        int c = i >> 6, kp = i & 63;
        w2t[i] = (c < 40) ? f2bf2(W2[(size_t)(2 * kp) * 40 + c], W2[(size_t)(2 * kp + 1) * 40 + c]) : 0u;
    }
}

// ---------------------------------------------------------------------------
// K1: MERGED [count+rank || MFMA GEMM1 + fused alpha1 epilogue].
// alpha1 computed straight from the MFMA accumulators (head h = tc>>1),
// width-16 shfl reduce over lr; hidden under the atomic tail.
__global__ __launch_bounds__(256) void count_gemm1(
    const int* __restrict__ dst0, int* __restrict__ cnt, int* __restrict__ rank,
    const float* __restrict__ A, const unsigned* __restrict__ w1t,
    unsigned* __restrict__ out, const float* __restrict__ asw,
    const float* __restrict__ adw, float* __restrict__ as1, float* __restrict__ ad1) {
    if (blockIdx.x < CNT_NB) {
        int e = blockIdx.x * 256 + threadIdx.x;
        if (e < NE) rank[e] = atomicAdd(&cnt[dst0[e]], 1);
        return;
    }
    __shared__ unsigned sA[64 * 68];
    __shared__ unsigned sB[128 * 68];
    int t = threadIdx.x;
    int row0 = (blockIdx.x - CNT_NB) * 64;
    for (int i = t; i < 64 * 32; i += 256) {
        int r = i >> 5, q = i & 31;
        int gr = row0 + r;
        float4 v = (gr < NN) ? *(const float4*)&A[(size_t)gr * 128 + q * 4]
                             : make_float4(0.f, 0.f, 0.f, 0.f);
        sA[r * 68 + q * 2]     = f2bf2(v.x, v.y);
        sA[r * 68 + q * 2 + 1] = f2bf2(v.z, v.w);
    }
    for (int i = t; i < 128 * 16; i += 256) {
        int c = i >> 4, q = i & 15;
        *(uint4*)&sB[c * 68 + q * 4] = *(const uint4*)&w1t[c * 64 + q * 4];
    }
    __syncthreads();
    int wv = t >> 6, lane = t & 63;
    int lr = lane & 15, kgrp = lane >> 4;
    f32x4_t acc[8];
#pragma unroll
    for (int i = 0; i < 8; ++i) acc[i] = (f32x4_t){0.f, 0.f, 0.f, 0.f};
    int arow = wv * 16 + lr;
#pragma unroll
    for (int kt = 0; kt < 4; ++kt) {
        int kw = kt * 16 + kgrp * 4;
        s16x8_t af = *(const s16x8_t*)&sA[arow * 68 + kw];
#pragma unroll
        for (int tc = 0; tc < 8; ++tc) {
            s16x8_t bf = *(const s16x8_t*)&sB[(tc * 16 + lr) * 68 + kw];
            acc[tc] = __builtin_amdgcn_mfma_f32_16x16x32_bf16(af, bf, acc[tc], 0, 0, 0);
        }
    }
    int orow0 = row0 + wv * 16 + kgrp * 4;
#pragma unroll
    for (int tc = 0; tc < 8; ++tc) {
#pragma unroll
        for (int r = 0; r < 4; ++r) {
            float v = acc[tc][r];
            float other = __shfl_xor(v, 1);
            int gr = orow0 + r;
            if (!(lane & 1) && gr < NN)
                out[(size_t)gr * 64 + tc * 8 + (lr >> 1)] = f2bf2(v, other);
        }
    }
    // fused alpha1 from accumulators (fp32, pre-rounding).
    float pa[4][4], pd[4][4];
#pragma unroll
    for (int h = 0; h < 4; ++h)
#pragma unroll
        for (int r = 0; r < 4; ++r) { pa[h][r] = 0.f; pd[h][r] = 0.f; }
#pragma unroll
    for (int tc = 0; tc < 8; ++tc) {
        int col = tc * 16 + lr;
        float wa = asw[col], wd = adw[col];
        int h = tc >> 1;
#pragma unroll
        for (int r = 0; r < 4; ++r) {
            pa[h][r] += acc[tc][r] * wa;
            pd[h][r] += acc[tc][r] * wd;
        }
    }
#pragma unroll
    for (int h = 0; h < 4; ++h)
#pragma unroll
        for (int r = 0; r < 4; ++r)
#pragma unroll
            for (int d = 8; d >= 1; d >>= 1) {
                pa[h][r] += __shfl_xor(pa[h][r], d, 16);
                pd[h][r] += __shfl_xor(pd[h][r], d, 16);
            }
    if (lr == 0) {
#pragma unroll
        for (int r = 0; r < 4; ++r) {
            int gr = orow0 + r;
            if (gr < NN) {
#pragma unroll
                for (int h = 0; h < 4; ++h) {
                    as1[gr * 4 + h] = pa[h][r];
                    ad1[gr * 4 + h] = pd[h][r];
                }
            }
        }
    }
}

// ---------------------------------------------------------------------------
// K2: scan1 — per-block exclusive scan of cnt (partial) + raw block sums.
__global__ __launch_bounds__(256) void scan1_kernel(
    const int* __restrict__ cnt, int* __restrict__ off, int* __restrict__ bsum) {
    __shared__ int tmp[256];
    int t = threadIdx.x;
    int g = blockIdx.x * 256 + t;
    int v = (g < NN) ? cnt[g] : 0;
    tmp[t] = v;
    __syncthreads();
#pragma unroll
    for (int d = 1; d < 256; d <<= 1) {
        int u = (t >= d) ? tmp[t - d] : 0;
        __syncthreads();
        tmp[t] += u;
        __syncthreads();
    }
    if (g < NN) off[g] = tmp[t] - v;
    if (t == 255) bsum[blockIdx.x] = tmp[255];
}

// ---------------------------------------------------------------------------
// K3: MERGED [scan-finalize || fill].
__global__ __launch_bounds__(256) void scanf_fill(
    const int* __restrict__ off, const int* __restrict__ bsum,
    const int* __restrict__ cnt, int* __restrict__ offF,
    const int* __restrict__ src0, const int* __restrict__ dst0,
    const float* __restrict__ eattr, const float* __restrict__ wf1,
    const float* __restrict__ wf2, const int* __restrict__ rank,
    uint4* __restrict__ epk) {
    __shared__ int tmp[256];
    int t = threadIdx.x;
    int v = (t < SCAN_NB) ? bsum[t] : 0;
    tmp[t] = v;
    __syncthreads();
#pragma unroll
    for (int d = 1; d < 256; d <<= 1) {
        int u = (t >= d) ? tmp[t - d] : 0;
        __syncthreads();
        tmp[t] += u;
        __syncthreads();
    }
    if (blockIdx.x < SCAN_NB) {
        int pre = (blockIdx.x == 0) ? 0 : tmp[blockIdx.x - 1];
        int g = blockIdx.x * 256 + t;
        if (g < NN) {
            int o = off[g] + pre;
            offF[g] = o;
            if (g == NN - 1) offF[NN] = o + cnt[g];
        }
        return;
    }
    int base = (blockIdx.x - SCAN_NB) * 1024 + t;
#pragma unroll
    for (int k = 0; k < 4; ++k) {
        int e = base + k * 256;
        if (e >= NE) continue;
        float a[5];
#pragma unroll
        for (int j = 0; j < 5; ++j) a[j] = eattr[(size_t)e * 5 + j];
        float o[4];
#pragma unroll
        for (int h = 0; h < 4; ++h) {
            float s = 0.f;
#pragma unroll
            for (int j = 0; j < 5; ++j) s += a[j] * wf1[j * 4 + h];
            o[h] = s;
        }
        float s2 = 0.f;
#pragma unroll
        for (int j = 0; j < 5; ++j) s2 += a[j] * wf2[j];
        int d = dst0[e];
        int blk = d >> 8;
        int pre = (blk == 0) ? 0 : tmp[blk - 1];
        int pos = off[d] + pre + rank[e];
        epk[pos] = make_uint4((unsigned)src0[e], f2bf2(o[0], o[1]), f2bf2(o[2], o[3]),
                              __float_as_uint(s2));
    }
}

// ---------------------------------------------------------------------------
// K4: layer-1 GAT aggregation. 4 nodes/wave, 16 lanes/node.
__global__ __launch_bounds__(256) void gat1_kernel(
    const uint4* __restrict__ epk, const int* __restrict__ off,
    const unsigned* __restrict__ xs1u,
    const float4* __restrict__ as1, const float4* __restrict__ ad1,
    const float* __restrict__ b1, const float* __restrict__ g1, const float* __restrict__ be1,
    const float* __restrict__ rm1, const float* __restrict__ rv1, unsigned* __restrict__ h1u) {
    __shared__ int   lds_s[4][4][16];
    __shared__ float lds_w[4][4][16][4];
    int wave = threadIdx.x >> 6;
    int lane = threadIdx.x & 63;
    int g = lane >> 4;
    int lr = lane & 15;
    int qh = lr >> 2;
    int n = blockIdx.x * 16 + wave * 4 + g;
    int e0 = off[n];
    int deg = off[n + 1] - e0;
    float4 adn = ad1[n];
    float4 asn = as1[n];
    f32x2_t acc2[4];
#pragma unroll
    for (int k = 0; k < 4; ++k) acc2[k] = (f32x2_t){0.f, 0.f};
    float ds0 = 0.f, ds1 = 0.f, ds2 = 0.f, ds3 = 0.f;
    float s0 = 0.f, s1 = 0.f, s2 = 0.f, s3 = 0.f;
    int mc = (deg + 15) >> 4;
    mc = max(mc, __shfl_xor(mc, 16));
    mc = max(mc, __shfl_xor(mc, 32));

    for (int ch = 0; ch < mc; ++ch) {
        int i = ch * 16 + lr;
        int s = 0;
        float w0 = 0.f, w1 = 0.f, w2 = 0.f, w3 = 0.f;
        if (i < deg) {
            uint4 ep = epk[e0 + i];
            s = (int)ep.x;
            float ax = bf_lo(ep.y), ay = bf_hi(ep.y);
            float az = bf_lo(ep.z), aw = bf_hi(ep.z);
            float4 av = as1[s];
            float a0 = av.x + adn.x + ax;
            float a1 = av.y + adn.y + ay;
            float a2 = av.z + adn.z + az;
            float a3 = av.w + adn.w + aw;
            a0 = a0 >= 0.f ? a0 : 0.2f * a0;
            a1 = a1 >= 0.f ? a1 : 0.2f * a1;
            a2 = a2 >= 0.f ? a2 : 0.2f * a2;
            a3 = a3 >= 0.f ? a3 : 0.2f * a3;
            w0 = __expf(a0); w1 = __expf(a1); w2 = __expf(a2); w3 = __expf(a3);
            ds0 += w0; ds1 += w1; ds2 += w2; ds3 += w3;
            s0 += ax; s1 += ay; s2 += az; s3 += aw;
        }
        lds_s[wave][g][lr] = s;
        *(float4*)&lds_w[wave][g][lr][0] = make_float4(w0, w1, w2, w3);
        __builtin_amdgcn_wave_barrier();
        int cn = deg - ch * 16;
        cn = cn > 16 ? 16 : (cn < 0 ? 0 : cn);
        int cnr = (cn + 3) & ~3;
        for (int j = 0; j < cnr; j += 4) {
            int sj0 = lds_s[wave][g][j];
            int sj1 = lds_s[wave][g][j + 1];
            int sj2 = lds_s[wave][g][j + 2];
            int sj3 = lds_s[wave][g][j + 3];
            float ww0 = lds_w[wave][g][j][qh];
            float ww1 = lds_w[wave][g][j + 1][qh];
            float ww2 = lds_w[wave][g][j + 2][qh];
            float ww3 = lds_w[wave][g][j + 3][qh];
            uint4 u0 = *(const uint4*)&xs1u[(size_t)sj0 * 64 + lr * 4];
            uint4 u1 = *(const uint4*)&xs1u[(size_t)sj1 * 64 + lr * 4];
            uint4 u2 = *(const uint4*)&xs1u[(size_t)sj2 * 64 + lr * 4];
            uint4 u3 = *(const uint4*)&xs1u[(size_t)sj3 * 64 + lr * 4];
            f32x2_t W0 = {ww0, ww0}, W1v = {ww1, ww1}, W2v = {ww2, ww2}, W3v = {ww3, ww3};
            acc2[0] += W0 * bfpair(u0.x); acc2[1] += W0 * bfpair(u0.y);
            acc2[2] += W0 * bfpair(u0.z); acc2[3] += W0 * bfpair(u0.w);
            acc2[0] += W1v * bfpair(u1.x); acc2[1] += W1v * bfpair(u1.y);
            acc2[2] += W1v * bfpair(u1.z); acc2[3] += W1v * bfpair(u1.w);
            acc2[0] += W2v * bfpair(u2.x); acc2[1] += W2v * bfpair(u2.y);
            acc2[2] += W2v * bfpair(u2.z); acc2[3] += W2v * bfpair(u2.w);
            acc2[0] += W3v * bfpair(u3.x); acc2[1] += W3v * bfpair(u3.y);
            acc2[2] += W3v * bfpair(u3.z); acc2[3] += W3v * bfpair(u3.w);
        }
        __builtin_amdgcn_wave_barrier();
    }
#pragma unroll
    for (int d = 8; d >= 1; d >>= 1) {
        ds0 += __shfl_xor(ds0, d, 16); ds1 += __shfl_xor(ds1, d, 16);
        ds2 += __shfl_xor(ds2, d, 16); ds3 += __shfl_xor(ds3, d, 16);
        s0 += __shfl_xor(s0, d, 16);   s1 += __shfl_xor(s1, d, 16);
        s2 += __shfl_xor(s2, d, 16);   s3 += __shfl_xor(s3, d, 16);
    }
    float invd = 1.f / fmaxf((float)deg, 1.f);
    float aL0 = asn.x + adn.x + s0 * invd;
    float aL1 = asn.y + adn.y + s1 * invd;
    float aL2 = asn.z + adn.z + s2 * invd;
    float aL3 = asn.w + adn.w + s3 * invd;
    aL0 = aL0 >= 0.f ? aL0 : 0.2f * aL0;
    aL1 = aL1 >= 0.f ? aL1 : 0.2f * aL1;
    aL2 = aL2 >= 0.f ? aL2 : 0.2f * aL2;
    aL3 = aL3 >= 0.f ? aL3 : 0.2f * aL3;
    float ws0 = __expf(aL0), ws1 = __expf(aL1), ws2 = __expf(aL2), ws3 = __expf(aL3);
    float wself = qh == 0 ? ws0 : (qh == 1 ? ws1 : (qh == 2 ? ws2 : ws3));
    float dh = qh == 0 ? ds0 + ws0 : (qh == 1 ? ds1 + ws1 : (qh == 2 ? ds2 + ws2 : ds3 + ws3));
    uint4 us = *(const uint4*)&xs1u[(size_t)n * 64 + lr * 4];
    f32x2_t Ws = {wself, wself};
    acc2[0] += Ws * bfpair(us.x); acc2[1] += Ws * bfpair(us.y);
    acc2[2] += Ws * bfpair(us.z); acc2[3] += Ws * bfpair(us.w);
    float inv = 1.f / (dh + 1e-16f);
    int c = lr * 8;
    uint4 ou;
    unsigned* op = (unsigned*)&ou;
#pragma unroll
    for (int k2 = 0; k2 < 4; ++k2) {
        int c0 = c + 2 * k2, c1 = c + 2 * k2 + 1;
        float o0 = acc2[k2][0] * inv + b1[c0];
        float o1 = acc2[k2][1] * inv + b1[c1];
        float sc0 = g1[c0] * rsqrtf(rv1[c0] + 1e-5f);
        float sc1 = g1[c1] * rsqrtf(rv1[c1] + 1e-5f);
        o0 = (o0 - rm1[c0]) * sc0 + be1[c0];
        o1 = (o1 - rm1[c1]) * sc1 + be1[c1];
        o0 = o0 > 0.f ? o0 : __expf(o0) - 1.f;
        o1 = o1 > 0.f ? o1 : __expf(o1) - 1.f;
        op[k2] = f2bf2(o0, o1);
    }
    *(uint4*)&h1u[(size_t)n * 64 + lr * 4] = ou;
}

// ---------------------------------------------------------------------------
// K5: MFMA GEMM2 + fused alpha2 epilogue.
__global__ __launch_bounds__(256) void gemm2_alpha2(
    const unsigned* __restrict__ A, const unsigned* __restrict__ w2t,
    unsigned* __restrict__ out, const float* __restrict__ asw,
    const float* __restrict__ adw, float* __restrict__ as2, float* __restrict__ ad2) {
    __shared__ unsigned sA[64 * 68];
    __shared__ unsigned sB[48 * 68];
    __shared__ unsigned hX[64 * 24];
    int t = threadIdx.x;
    int row0 = blockIdx.x * 64;
    for (int i = t; i < 64 * 16; i += 256) {
        int r = i >> 4, q = i & 15;
        int gr = row0 + r;
        uint4 v = (gr < NN) ? *(const uint4*)&A[(size_t)gr * 64 + q * 4]
                            : make_uint4(0u, 0u, 0u, 0u);
        *(uint4*)&sA[r * 68 + q * 4] = v;
    }
    for (int i = t; i < 48 * 16; i += 256) {
        int c = i >> 4, q = i & 15;
        *(uint4*)&sB[c * 68 + q * 4] = *(const uint4*)&w2t[c * 64 + q * 4];
    }
    __syncthreads();
    int wv = t >> 6, lane = t & 63;
    int lr = lane & 15, kgrp = lane >> 4;
    f32x4_t acc[3];
#pragma unroll
    for (int i = 0; i < 3; ++i) acc[i] = (f32x4_t){0.f, 0.f, 0.f, 0.f};
    int arow = wv * 16 + lr;
#pragma unroll
    for (int kt = 0; kt < 4; ++kt) {
        int kw = kt * 16 + kgrp * 4;
        s16x8_t af = *(const s16x8_t*)&sA[arow * 68 + kw];
#pragma unroll
        for (int tc = 0; tc < 3; ++tc) {
            s16x8_t bf = *(const s16x8_t*)&sB[(tc * 16 + lr) * 68 + kw];
            acc[tc] = __builtin_amdgcn_mfma_f32_16x16x32_bf16(af, bf, acc[tc], 0, 0, 0);
        }
    }
    int orow0l = wv * 16 + kgrp * 4;
#pragma unroll
    for (int tc = 0; tc < 3; ++tc) {
#pragma unroll
        for (int r = 0; r < 4; ++r) {
            float v = acc[tc][r];
            float other = __shfl_xor(v, 1);
            int lrow = orow0l + r;
            int gr = row0 + lrow;
            if (!(lane & 1) && (tc < 2 || lr < 8)) {
                unsigned u = f2bf2(v, other);
                hX[lrow * 24 + tc * 8 + (lr >> 1)] = u;
                if (gr < NN) out[(size_t)gr * 32 + tc * 8 + (lr >> 1)] = u;
            }
        }
    }
    __syncthreads();
    {
        int r = t >> 2, q = t & 3;
        int gr = row0 + r;
        float pa = 0.f, pd = 0.f;
#pragma unroll
        for (int k = 0; k < 5; ++k) {
            int cidx = q * 5 + k;
            unsigned u = hX[r * 24 + cidx];
            int c = cidx * 2;
            pa += bf_lo(u) * asw[c] + bf_hi(u) * asw[c + 1];
            pd += bf_lo(u) * adw[c] + bf_hi(u) * adw[c + 1];
        }
        pa += __shfl_xor(pa, 1, 4); pa += __shfl_xor(pa, 2, 4);
        pd += __shfl_xor(pd, 1, 4); pd += __shfl_xor(pd, 2, 4);
        if (q == 0 && gr < NN) { as2[gr] = pa; ad2[gr] = pd; }
    }
}

// ---------------------------------------------------------------------------
// K6: layer-2 GAT aggregation + bias + BN + log_softmax.
__global__ __launch_bounds__(256) void gat2_kernel(
    const uint4* __restrict__ epk, const int* __restrict__ off,
    const unsigned* __restrict__ xs2u,
    const float* __restrict__ as2, const float* __restrict__ ad2,
    const float* __restrict__ b2, const float* __restrict__ g2, const float* __restrict__ be2,
    const float* __restrict__ rm2, const float* __restrict__ rv2, float* __restrict__ outp) {
    __shared__ int   lds_s[4][72];
    __shared__ float lds_w[4][72];
    int wid = (blockIdx.x * 256 + threadIdx.x) >> 6;
    if (wid >= NN) return;
    int lane = threadIdx.x & 63;
    int warp = threadIdx.x >> 6;
    int n = wid;
    int e0 = off[n], e1 = off[n + 1];
    int deg = e1 - e0;
    int grp3 = lane / 20;
    int col = lane - grp3 * 20;
    bool act = grp3 < 3;
    int grpo = act ? grp3 : 0;
    if (lane < 8) {
        lds_s[warp][64 + lane] = 0;
        lds_w[warp][64 + lane] = 0.f;
    }
    float adn = ad2[n];
    float asn = as2[n];
    f32x2_t acc2 = {0.f, 0.f};
    float dsum = 0.f, aesum = 0.f;

    for (int base = 0; base < deg; base += 64) {
        int i = base + lane;
        int cn = min(64, deg - base);
        int s = 0;
        float w = 0.f;
        if (i < deg) {
            uint4 ep = epk[e0 + i];
            s = (int)ep.x;
            float ae = __uint_as_float(ep.w);
            float a = as2[s] + adn + ae;
            a = a >= 0.f ? a : 0.2f * a;
            w = __expf(a);
            dsum += w;
            aesum += ae;
        }
        lds_s[warp][lane] = s;
        lds_w[warp][lane] = w;
        __builtin_amdgcn_wave_barrier();
        int cnr = ((cn + 11) / 12) * 12;            // <= 72; jj max = 71
        for (int j = 0; j < cnr; j += 12) {
            int jj0 = j + grpo, jj1 = jj0 + 3, jj2 = jj0 + 6, jj3 = jj0 + 9;
            int sj0 = lds_s[warp][jj0];
            int sj1 = lds_s[warp][jj1];
            int sj2 = lds_s[warp][jj2];
            int sj3 = lds_s[warp][jj3];
            float w0 = act ? lds_w[warp][jj0] : 0.f;
            float w1 = act ? lds_w[warp][jj1] : 0.f;
            float w2 = act ? lds_w[warp][jj2] : 0.f;
            float w3 = act ? lds_w[warp][jj3] : 0.f;
            unsigned u0 = xs2u[(size_t)sj0 * 32 + col];
            unsigned u1 = xs2u[(size_t)sj1 * 32 + col];
            unsigned u2 = xs2u[(size_t)sj2 * 32 + col];
            unsigned u3 = xs2u[(size_t)sj3 * 32 + col];
            acc2 += (f32x2_t){w0, w0} * bfpair(u0);
            acc2 += (f32x2_t){w1, w1} * bfpair(u1);
            acc2 += (f32x2_t){w2, w2} * bfpair(u2);
            acc2 += (f32x2_t){w3, w3} * bfpair(u3);
        }
        __builtin_amdgcn_wave_barrier();
    }
    {
        float p0 = __shfl(acc2[0], (lane + 20) & 63);
        float p1 = __shfl(acc2[1], (lane + 20) & 63);
        float q0 = __shfl(acc2[0], (lane + 40) & 63);
        float q1 = __shfl(acc2[1], (lane + 40) & 63);
        acc2[0] += p0 + q0;
        acc2[1] += p1 + q1;
    }
#pragma unroll
    for (int d = 32; d >= 1; d >>= 1) {
        dsum += __shfl_xor(dsum, d);
        aesum += __shfl_xor(aesum, d);
    }
    float invd = 1.f / fmaxf((float)deg, 1.f);
    float aL = asn + adn + aesum * invd;
    aL = aL >= 0.f ? aL : 0.2f * aL;
    float wself = __expf(aL);
    float denom = dsum + wself;

    float v0 = 0.f, v1 = 0.f;
    if (lane < 20) {
        unsigned u = xs2u[(size_t)n * 32 + lane];
        acc2[0] += wself * bf_lo(u);
        acc2[1] += wself * bf_hi(u);
        int c = lane * 2;
        float inv = 1.f / (denom + 1e-16f);
        v0 = acc2[0] * inv + b2[c];
        v1 = acc2[1] * inv + b2[c + 1];
        float sc0 = g2[c] * rsqrtf(rv2[c] + 1e-5f);
        float sc1 = g2[c + 1] * rsqrtf(rv2[c + 1] + 1e-5f);
        v0 = (v0 - rm2[c]) * sc0 + be2[c];
        v1 = (v1 - rm2[c + 1]) * sc1 + be2[c + 1];
    }
    float mx = (lane < 20) ? fmaxf(v0, v1) : -3.0e38f;
#pragma unroll
    for (int d = 32; d >= 1; d >>= 1) mx = fmaxf(mx, __shfl_xor(mx, d));
    float ex = (lane < 20) ? __expf(v0 - mx) + __expf(v1 - mx) : 0.f;
#pragma unroll
    for (int d = 32; d >= 1; d >>= 1) ex += __shfl_xor(ex, d);
    if (lane < 20) {
        float ls = __logf(ex);
        *(float2*)&outp[(size_t)n * 40 + lane * 2] = make_float2(v0 - mx - ls, v1 - mx - ls);
    }
}

// ---------------------------------------------------------------------------
extern "C" void kernel_launch(void* const* d_in, const int* in_sizes, int n_in,
                              void* d_out, int out_size, void* d_ws, size_t ws_size,
                              hipStream_t stream) {
    const float* x     = (const float*)d_in[0];
    const int*   ei    = (const int*)d_in[1];
    const float* eattr = (const float*)d_in[2];
    const float* W1    = (const float*)d_in[3];
    const float* as1w  = (const float*)d_in[4];
    const float* ad1w  = (const float*)d_in[5];
    const float* ae1w  = (const float*)d_in[6];
    const float* We1   = (const float*)d_in[7];
    const float* b1    = (const float*)d_in[8];
    const float* W2    = (const float*)d_in[9];
    const float* as2w  = (const float*)d_in[10];
    const float* ad2w  = (const float*)d_in[11];
    const float* ae2w  = (const float*)d_in[12];
    const float* We2   = (const float*)d_in[13];
    const float* b2    = (const float*)d_in[14];
    const float* g1    = (const float*)d_in[15];
    const float* be1   = (const float*)d_in[16];
    const float* rm1   = (const float*)d_in[17];
    const float* rv1   = (const float*)d_in[18];
    const float* g2    = (const float*)d_in[19];
    const float* be2   = (const float*)d_in[20];
    const float* rm2   = (const float*)d_in[21];
    const float* rv2   = (const float*)d_in[22];

    const int* src0 = ei;
    const int* dst0 = ei + NE;

    char* p = (char*)d_ws;
    auto take = [&](size_t nbytes) {
        void* r = (void*)p;
        p += (nbytes + 255) & ~(size_t)255;
        return r;
    };
    float*    wf1    = (float*)take(80);
    float*    wf2    = (float*)take(20);
    unsigned* w1t    = (unsigned*)take((size_t)128 * 64 * 4);
    unsigned* w2t    = (unsigned*)take((size_t)48 * 64 * 4);
    int*      cnt    = (int*)take((size_t)NN * 4);
    int*      off    = (int*)take((size_t)(NN + 1) * 4);
    int*      offF   = (int*)take((size_t)(NN + 1) * 4);
    int*      bsum   = (int*)take((size_t)SCAN_NB * 4);
    int*      rank   = (int*)take((size_t)NE * 4);
    uint4*    epk    = (uint4*)take((size_t)NE * 16);
    float*    as1    = (float*)take((size_t)NN * 16);
    float*    ad1    = (float*)take((size_t)NN * 16);
    float*    as2    = (float*)take((size_t)NN * 4);
    float*    ad2    = (float*)take((size_t)NN * 4);
    unsigned* xs1u   = (unsigned*)take((size_t)NN * 256);  // 64 uints/row
    unsigned* h1u    = (unsigned*)take((size_t)NN * 256);
    unsigned* xs2u   = (unsigned*)take((size_t)NN * 128);  // 32 uints/row

    prep_kernel<<<SCAN_NB, 256, 0, stream>>>(We1, ae1w, We2, ae2w, W1, W2, wf1, wf2,
                                             w1t, w2t, cnt);
    count_gemm1<<<CNT_NB + G1_NB, 256, 0, stream>>>(dst0, cnt, rank, x, w1t, xs1u,
                                                    as1w, ad1w, as1, ad1);
    scan1_kernel<<<SCAN_NB, 256, 0, stream>>>(cnt, off, bsum);
    scanf_fill<<<SCAN_NB + FF_NB, 256, 0, stream>>>(off, bsum, cnt, offF, src0, dst0,
                                                    eattr, wf1, wf2, rank, epk);
    gat1_kernel<<<NN / 16, 256, 0, stream>>>(epk, offF, xs1u, (const float4*)as1,
                                             (const float4*)ad1, b1, g1, be1, rm1, rv1, h1u);
    gemm2_alpha2<<<(NN + 63) / 64, 256, 0, stream>>>(h1u, w2t, xs2u, as2w, ad2w, as2, ad2);
    gat2_kernel<<<(NN + 3) / 4, 256, 0, stream>>>(epk, offF, xs2u, as2, ad2,
                                                  b2, g2, be2, rm2, rv2, (float*)d_out);
}